// Round 15
// baseline (263.950 us; speedup 1.0000x reference)
//
#include <hip/hip_runtime.h>
#include <stdint.h>

typedef __bf16 bf16x8 __attribute__((ext_vector_type(8)));
typedef float f32x4 __attribute__((ext_vector_type(4)));

#define BB 8
#define SS 2048
#define HH 1024

// compact triangular scores: 128x128 tiles in COMPACTED key/query space.
#define TILE_B   32768ll
#define NTRI     136
#define BATCH_B  (NTRI * TILE_B)

// ws layout (bytes). Peak ~163 MiB (validated r13/r14).
#define OFF_Q      0ll
#define OFF_K      33554432ll
#define OFF_VT     67108864ll
#define OFF_MASK   100663296ll
#define OFF_MEANV  100679680ll
#define OFF_VIDX   100712448ll
#define OFF_NV     100843520ll
#define OFF_TMP    101711872ll
#define OFF_XBF    (OFF_TMP)
#define OFF_WBF    (OFF_TMP + 33554432ll)
#define OFF_VTC    (OFF_TMP)
#define OFF_SCORES (OFF_TMP + 33554432ll)

__device__ __forceinline__ unsigned short f2bf(float f) {
  unsigned int u = __float_as_uint(f);
  u += 0x7FFFu + ((u >> 16) & 1u);   // RTNE
  return (unsigned short)(u >> 16);
}
__device__ __forceinline__ float bf2f(unsigned short u) {
  return __uint_as_float(((unsigned int)u) << 16);
}

__device__ __forceinline__ void gl_lds16(const void* g, void* l) {
  __builtin_amdgcn_global_load_lds(
      (const __attribute__((address_space(1))) void*)g,
      (__attribute__((address_space(3))) void*)l, 16, 0, 0);
}

// ------- mask canonicalizer (uint8 / int32 / float32), 1024-thr vectorized --
__global__ __launch_bounds__(1024) void canon_mask(
    const unsigned char* __restrict__ m, unsigned char* __restrict__ out) {
  __shared__ int cnt[4];
  const int t = threadIdx.x;
  if (t < 4) cnt[t] = 0;
  __syncthreads();
  uint4 v = ((const uint4*)m)[t];
  const unsigned char* pb = (const unsigned char*)&v;
  int loc[4] = {0, 0, 0, 0};
#pragma unroll
  for (int j = 0; j < 16; ++j)
    if (pb[j]) loc[j & 3]++;
#pragma unroll
  for (int r = 0; r < 4; ++r)
    if (loc[r]) atomicAdd(&cnt[r], loc[r]);
  __syncthreads();
  const int c0 = cnt[0], c1 = cnt[1], c2 = cnt[2], c3 = cnt[3];
  unsigned char ob[16];
  if (c0 > 0 && c1 == 0 && c2 == 0 && c3 == 0) {        // int32 0/1
    const int* mi = (const int*)m;
#pragma unroll
    for (int j = 0; j < 16; ++j) ob[j] = mi[t * 16 + j] ? 1 : 0;
  } else if (c0 == 0 && (c2 > 0 || c3 > 0)) {           // float32
    const float* mf = (const float*)m;
#pragma unroll
    for (int j = 0; j < 16; ++j) ob[j] = (mf[t * 16 + j] != 0.0f) ? 1 : 0;
  } else {                                              // uint8 bool
#pragma unroll
    for (int j = 0; j < 16; ++j) ob[j] = pb[j] ? 1 : 0;
  }
  ((uint4*)out)[t] = *(const uint4*)ob;
}

// ------- per-batch compaction: vidx (compact->orig, zero-padded), nv --------
__global__ __launch_bounds__(256) void build_compact(
    const unsigned char* __restrict__ mask, int* __restrict__ vidx,
    int* __restrict__ nv) {
  const int b = blockIdx.x;
  const int t = threadIdx.x;
  __shared__ int cnt[256];
  __shared__ int totalS;
  const unsigned char* mb = mask + b * SS;
  unsigned char m[8];
  int c = 0;
#pragma unroll
  for (int j = 0; j < 8; ++j) { m[j] = mb[t * 8 + j]; c += m[j] ? 1 : 0; }
  cnt[t] = c;
  __syncthreads();
  int base = 0;
  for (int i = 0; i < t; ++i) base += cnt[i];
  if (t == 255) totalS = base + c;
  int pos = base;
  int* vb = vidx + b * SS;
#pragma unroll
  for (int j = 0; j < 8; ++j) {
    const int s = t * 8 + j;
    if (m[j]) { vb[pos] = s; ++pos; }
  }
  __syncthreads();
  const int total = totalS;
  if (t == 0) nv[b] = total;
  for (int idx = total + t; idx < SS; idx += 256) vb[idx] = 0;
}

__global__ void cvt_f32_bf16(const float* __restrict__ in,
                             unsigned short* __restrict__ out, int n4) {
  int i = blockIdx.x * blockDim.x + threadIdx.x;
  int stride = gridDim.x * blockDim.x;
  for (; i < n4; i += stride) {
    float4 v = ((const float4*)in)[i];
    ushort4 o;
    o.x = f2bf(v.x); o.y = f2bf(v.y); o.z = f2bf(v.z); o.w = f2bf(v.w);
    ((ushort4*)out)[i] = o;
  }
}

__global__ void cvt_w3(const float* __restrict__ Wq, const float* __restrict__ Wk,
                       const float* __restrict__ Wv, unsigned short* __restrict__ out) {
  const int z = blockIdx.y;
  const float* src = (z == 0) ? Wq : (z == 1) ? Wk : Wv;
  unsigned short* dst = out + (long)z * (HH * HH);
  const int n4 = HH * HH / 4;
  int i = blockIdx.x * 256 + threadIdx.x;
  for (; i < n4; i += 256 * 256) {
    float4 v = ((const float4*)src)[i];
    ushort4 o;
    o.x = f2bf(v.x); o.y = f2bf(v.y); o.z = f2bf(v.z); o.w = f2bf(v.w);
    ((ushort4*)dst)[i] = o;
  }
}

// ------- Vtc[h][j] = Vt[h][vidx[j]] (zero-padded beyond nv) -----------------
__global__ __launch_bounds__(256) void vtc_gather(
    const unsigned short* __restrict__ Vt, const int* __restrict__ vidx,
    const int* __restrict__ nv, unsigned short* __restrict__ Vtc) {
  const int h = blockIdx.x;
  const int b = blockIdx.y;
  const int t = threadIdx.x;
  const unsigned short* src = Vt + ((long)b * HH + h) * SS;
  unsigned short* dst = Vtc + ((long)b * HH + h) * SS;
  const int n = nv[b];
  const int* vb = vidx + b * SS;
  const int j0 = t * 8;
  unsigned short o[8];
#pragma unroll
  for (int k = 0; k < 8; ++k) {
    const int j = j0 + k;
    o[k] = (j < n) ? src[vb[j]] : (unsigned short)0;
  }
  *(ushort4*)(dst + j0) = *(const ushort4*)o;
  *(ushort4*)(dst + j0 + 4) = *(const ushort4*)(o + 4);
}

// masked query rows -> uniform mean of V (meanV from gemm256 atomics)
__global__ __launch_bounds__(256) void fixup_masked(
    float* __restrict__ out, const unsigned char* __restrict__ mask,
    const float* __restrict__ sums) {
  const long row = blockIdx.x;
  if (mask[row]) return;
  const long b = row >> 11;
  const int t = threadIdx.x;
  float4 v = ((const float4*)(sums + b * HH))[t];
  v.x *= (1.f / 2048.f); v.y *= (1.f / 2048.f);
  v.z *= (1.f / 2048.f); v.w *= (1.f / 2048.f);
  ((float4*)(out + row * HH))[t] = v;
}

// ============ 256x256 fused QKV — 8-phase schedule, M-compacted Q/K =========
// grid (192,4): x = bm*3+z (z FASTEST -> full V blocks and exiting Q/K tiles
// interleave in dispatch order; fixes r14's 3-full-blocks-per-CU imbalance).
// z<2: A rows gathered through vidx at STAGE time; blocks past nv early-exit;
// epilogue writes contiguous compact Q/K rows.
// z==2: full-M V -> Vt (write-side transposed bounce) + fused meanV sums.
__global__ __launch_bounds__(512, 2) void gemm256(
    const unsigned short* __restrict__ Abase,
    const unsigned short* __restrict__ Bbase, long bStride,
    char* __restrict__ Cq, char* __restrict__ Ck, char* __restrict__ VtOut,
    const float* __restrict__ biasq, const float* __restrict__ biask,
    const float* __restrict__ biasv, float* __restrict__ meanV,
    const int* __restrict__ vidx, const int* __restrict__ nv) {
  extern __shared__ char smem[];
  const int tid = threadIdx.x;
  const int wave = tid >> 6, lane = tid & 63;
  const int wr = wave >> 2, wc = wave & 3;
  const int l15 = lane & 15, l4 = lane >> 4;
  const int xi = blockIdx.x;
  const int bm = xi / 3;                 // tile id (batch*8 + tileInBatch)
  const int bz = xi - bm * 3;            // matrix {Q,K,V}, fastest-varying
  const int bn = blockIdx.y;

  const int b = bm >> 3;                 // batch
  const int rInB = (bm & 7) * 256;       // tile row base within batch
  if (bz < 2 && rInB >= nv[b]) return;   // fully-masked Q/K tile: skip

  const char* B = (const char*)(Bbase + (long)bz * bStride);

  const int srow = tid >> 3;
  const int gslot = (tid & 7) ^ (srow & 7);
  // per-thread A source rows: compact-gathered (z<2) or identity (z==2)
  const int* vb = vidx + b * SS;
  const char* aS[4];
#pragma unroll
  for (int j = 0; j < 4; ++j) {
    const int r = rInB + srow + 64 * j;
    const int vr = (bz < 2) ? vb[r] : r;
    aS[j] = (const char*)Abase + ((long)b * SS + vr) * 2048 + gslot * 16;
  }
  const char* gB = B + ((long)bn * 256 + srow) * 2048 + gslot * 16;
  const int ldsStageW = wave << 10;

#define STG(kt_, type_, buf_) do { \
    char* _l = smem + ((buf_) << 16) + (((type_) >> 1) << 15) + \
               (((type_) & 1) << 14) + ldsStageW; \
    if ((type_) < 2) { \
      gl_lds16(aS[(type_) * 2]     + ((long)(kt_) << 7), _l); \
      gl_lds16(aS[(type_) * 2 + 1] + ((long)(kt_) << 7), _l + 8192); \
    } else { \
      const char* _g = gB + (((type_) & 1) ? 262144 : 0) + ((long)(kt_) << 7); \
      gl_lds16(_g, _l); \
      gl_lds16(_g + 131072, _l + 8192); \
    } } while (0)

  const int sw0 = ((l4 ^ (l15 & 7)) << 4);
  const int sw1 = (((4 + l4) ^ (l15 & 7)) << 4);
  const int aB0 = (wr << 14) + l15 * 128 + sw0;
  const int aB1 = (wr << 14) + l15 * 128 + sw1;
  const int bB0 = 32768 + ((wc >> 1) << 14) + (((wc & 1) << 6) + l15) * 128 + sw0;
  const int bB1 = 32768 + ((wc >> 1) << 14) + (((wc & 1) << 6) + l15) * 128 + sw1;

  f32x4 acc[8][4];
  const f32x4 z4 = {0.f, 0.f, 0.f, 0.f};
#pragma unroll
  for (int m = 0; m < 8; ++m)
#pragma unroll
    for (int n = 0; n < 4; ++n) acc[m][n] = z4;

  STG(0, 0, 0); STG(0, 1, 0); STG(0, 2, 0); STG(0, 3, 0);
  STG(1, 0, 1); STG(1, 1, 1); STG(1, 2, 1); STG(1, 3, 1);
  asm volatile("s_waitcnt vmcnt(8)" ::: "memory");
  __builtin_amdgcn_s_barrier();
  __builtin_amdgcn_sched_barrier(0);

  bf16x8 aC[4][2], bLo[2][2], bHi[2][2];

  for (int it = 0; it < 8; ++it) {
#pragma unroll
    for (int g = 0; g < 8; ++g) {
      const int buf = (g < 4) ? 0 : 65536;
      const int q = g & 3;
      if (q == 0) {
#pragma unroll
        for (int mm = 0; mm < 4; ++mm) {
          aC[mm][0] = *(const bf16x8*)(smem + buf + aB0 + mm * 2048);
          aC[mm][1] = *(const bf16x8*)(smem + buf + aB1 + mm * 2048);
        }
#pragma unroll
        for (int nn = 0; nn < 2; ++nn) {
          bLo[nn][0] = *(const bf16x8*)(smem + buf + bB0 + nn * 2048);
          bLo[nn][1] = *(const bf16x8*)(smem + buf + bB1 + nn * 2048);
        }
      } else if (q == 1) {
#pragma unroll
        for (int nn = 0; nn < 2; ++nn) {
          bHi[nn][0] = *(const bf16x8*)(smem + buf + bB0 + (2 + nn) * 2048);
          bHi[nn][1] = *(const bf16x8*)(smem + buf + bB1 + (2 + nn) * 2048);
        }
      } else if (q == 2) {
#pragma unroll
        for (int mm = 0; mm < 4; ++mm) {
          aC[mm][0] = *(const bf16x8*)(smem + buf + aB0 + (4 + mm) * 2048);
          aC[mm][1] = *(const bf16x8*)(smem + buf + aB1 + (4 + mm) * 2048);
        }
      }
      {
        const int u = it * 8 + g - 2;
        if (u >= 0) {
          const int kt = 2 + (u >> 2);
          if (kt < 16) {
            if (g == 0)      STG(kt, 0, 1);
            else if (g == 1) STG(kt, 1, 1);
            else if (g == 2) STG(kt, 2, 0);
            else if (g == 3) STG(kt, 3, 0);
            else if (g == 4) STG(kt, 0, 0);
            else if (g == 5) STG(kt, 1, 0);
            else if (g == 6) STG(kt, 2, 1);
            else             STG(kt, 3, 1);
          }
        }
      }
      __builtin_amdgcn_s_barrier();
      asm volatile("s_waitcnt lgkmcnt(0)" ::: "memory");
      __builtin_amdgcn_sched_barrier(0);
      __builtin_amdgcn_s_setprio(1);
      if (q == 0) {
#pragma unroll
        for (int mm = 0; mm < 4; ++mm)
#pragma unroll
          for (int nn = 0; nn < 2; ++nn) {
            acc[mm][nn] = __builtin_amdgcn_mfma_f32_16x16x32_bf16(
                aC[mm][0], bLo[nn][0], acc[mm][nn], 0, 0, 0);
            acc[mm][nn] = __builtin_amdgcn_mfma_f32_16x16x32_bf16(
                aC[mm][1], bLo[nn][1], acc[mm][nn], 0, 0, 0);
          }
      } else if (q == 1) {
#pragma unroll
        for (int mm = 0; mm < 4; ++mm)
#pragma unroll
          for (int nn = 0; nn < 2; ++nn) {
            acc[mm][2 + nn] = __builtin_amdgcn_mfma_f32_16x16x32_bf16(
                aC[mm][0], bHi[nn][0], acc[mm][2 + nn], 0, 0, 0);
            acc[mm][2 + nn] = __builtin_amdgcn_mfma_f32_16x16x32_bf16(
                aC[mm][1], bHi[nn][1], acc[mm][2 + nn], 0, 0, 0);
          }
      } else if (q == 2) {
#pragma unroll
        for (int mm = 0; mm < 4; ++mm)
#pragma unroll
          for (int nn = 0; nn < 2; ++nn) {
            acc[4 + mm][2 + nn] = __builtin_amdgcn_mfma_f32_16x16x32_bf16(
                aC[mm][0], bHi[nn][0], acc[4 + mm][2 + nn], 0, 0, 0);
            acc[4 + mm][2 + nn] = __builtin_amdgcn_mfma_f32_16x16x32_bf16(
                aC[mm][1], bHi[nn][1], acc[4 + mm][2 + nn], 0, 0, 0);
          }
      } else {
#pragma unroll
        for (int mm = 0; mm < 4; ++mm)
#pragma unroll
          for (int nn = 0; nn < 2; ++nn) {
            acc[4 + mm][nn] = __builtin_amdgcn_mfma_f32_16x16x32_bf16(
                aC[mm][0], bLo[nn][0], acc[4 + mm][nn], 0, 0, 0);
            acc[4 + mm][nn] = __builtin_amdgcn_mfma_f32_16x16x32_bf16(
                aC[mm][1], bLo[nn][1], acc[4 + mm][nn], 0, 0, 0);
          }
      }
      __builtin_amdgcn_s_setprio(0);
      __builtin_amdgcn_sched_barrier(0);
      if (q == 3) {
        if (g == 3 && it == 7)
          asm volatile("s_waitcnt vmcnt(0)" ::: "memory");
        else
          asm volatile("s_waitcnt vmcnt(4)" ::: "memory");
      }
      __builtin_amdgcn_s_barrier();
      asm volatile("" ::: "memory");
    }
  }
#undef STG

  const int rl0 = (wr << 7) + (l4 << 2);
  const int cl0 = (wc << 6) + l15;

  if (bz < 2) {
    // ---- row-major bounce; contiguous compact write ----
    const float* bias = (bz == 0) ? biasq : biask;
#pragma unroll
    for (int n = 0; n < 4; ++n) {
      const int cl = cl0 + n * 16;
      const float bv = bias[bn * 256 + cl];
      const int colx = cl ^ (l4 << 4);
#pragma unroll
      for (int m = 0; m < 8; ++m) {
        const int rl = rl0 + m * 16;
#pragma unroll
        for (int r = 0; r < 4; ++r)
          *(unsigned short*)(smem + (rl + r) * 512 + colx * 2) =
              f2bf(acc[m][n][r] + bv);
      }
    }
    __syncthreads();
    unsigned short* C = (unsigned short*)((bz == 0) ? Cq : Ck);
    const long rowg0 = (long)b * SS + rInB;
    const long colb0 = (long)bn * 512;
#pragma unroll
    for (int i = 0; i < 16; ++i) {
      const int s2 = i * 512 + tid;
      const int row = s2 >> 5;
      const int cb = s2 & 31;
      const int lb = (row * 512 + (cb << 4)) ^ (((row >> 2) & 3) << 5);
      *(uint4*)((char*)C + (rowg0 + row) * 2048 + colb0 + (cb << 4)) =
          *(const uint4*)(smem + lb);
    }
  } else {
    // ---- WRITE-side transposed bounce -> full Vt (r9-verified) ----
#pragma unroll
    for (int n = 0; n < 4; ++n) {
      const int h = cl0 + n * 16;
      const float bv = biasv[bn * 256 + h];
      const int xr = (h & 7) << 4;
#pragma unroll
      for (int m = 0; m < 8; ++m) {
        const int s0a = rl0 + m * 16;
        uint2 w;
        w.x = (unsigned)f2bf(acc[m][n][0] + bv) |
              ((unsigned)f2bf(acc[m][n][1] + bv) << 16);
        w.y = (unsigned)f2bf(acc[m][n][2] + bv) |
              ((unsigned)f2bf(acc[m][n][3] + bv) << 16);
        *(uint2*)(smem + h * 512 + ((s0a * 2) ^ xr)) = w;
      }
    }
    __syncthreads();
    char* VtB = VtOut + (long)b * (SS * HH * 2) + (long)(bm & 7) * 512;
#pragma unroll
    for (int i = 0; i < 16; ++i) {
      const int s2 = i * 512 + tid;
      const int h = s2 >> 5;
      const int cb = s2 & 31;
      const int lb = h * 512 + ((cb << 4) ^ ((h & 7) << 4));
      *(uint4*)(VtB + (long)(bn * 256 + h) * 4096 + cb * 16) =
          *(const uint4*)(smem + lb);
    }
    float* mv = meanV + (long)b * HH + (long)bn * 256;
#pragma unroll
    for (int n = 0; n < 4; ++n) {
      const int h = cl0 + n * 16;
      float s = 32.0f * biasv[bn * 256 + h];
#pragma unroll
      for (int m = 0; m < 8; ++m)
        s += acc[m][n][0] + acc[m][n][1] + acc[m][n][2] + acc[m][n][3];
      atomicAdd(&mv[h], s);
    }
  }
}

// -------- 128x128 ring-4 core: SCORES in compact space (pure triangular) ----
__global__ __launch_bounds__(256, 2) void gemm128s(
    const unsigned short* __restrict__ Qc, const unsigned short* __restrict__ Kc,
    char* __restrict__ scoresBase, const int* __restrict__ nv) {
  __shared__ __align__(16) char smem[65536];
  const int tid = threadIdx.x;
  const int wave = tid >> 6, lane = tid & 63;
  const int wr = wave >> 1, wc = wave & 1;
  const int l15 = lane & 15, l4 = lane >> 4;
  const int bz = blockIdx.y;

  int t0 = blockIdx.x, bm = 0, a_ = 0;
  while (a_ + bm + 1 <= t0) { ++bm; a_ += bm; }
  const int bn = t0 - a_;

  const int nt = (nv[bz] + 127) >> 7;
  if (bm >= nt) return;

  const unsigned short* A = Qc + (long)bz * SS * HH;
  const unsigned short* B = Kc + (long)bz * SS * HH;

  const int s0 = tid, s1 = tid + 256;
  const int rA0 = ((s0 >> 3) << 1) | (((s0 >> 2) & 1) ^ ((s0 >> 4) & 1));
  const int cA0 = (s0 & 3) ^ (rA0 & 3);
  const int rA1 = ((s1 >> 3) << 1) | (((s1 >> 2) & 1) ^ ((s1 >> 4) & 1));
  const int cA1 = (s1 & 3) ^ (rA1 & 3);
  const char* aG0 = (const char*)A + (long)(bm * 128 + rA0) * 2048 + cA0 * 16;
  const char* aG1 = (const char*)A + (long)(bm * 128 + rA1) * 2048 + cA1 * 16;
  const char* bG0 = (const char*)B + (long)(bn * 128 + rA0) * 2048 + cA0 * 16;
  const char* bG1 = (const char*)B + (long)(bn * 128 + rA1) * 2048 + cA1 * 16;
  const int ldsL0 = wave << 10;
  const int ldsL1 = 4096 + (wave << 10);

#define STG(t_) do { \
    char* _p = smem + (((t_) & 3) << 14); \
    const long _ko = (long)(t_) << 6; \
    gl_lds16(aG0 + _ko, _p + ldsL0); \
    gl_lds16(aG1 + _ko, _p + ldsL1); \
    gl_lds16(bG0 + _ko, _p + 8192 + ldsL0); \
    gl_lds16(bG1 + _ko, _p + 8192 + ldsL1); } while (0)

  const int baseSwz = ((l15 * 64 + (l4 << 4)) ^ ((l15 & 7) << 4));
  const int rdA = (wr << 12) + baseSwz;
  const int rdB = 8192 + (wc << 12) + baseSwz;

  f32x4 acc[4][4];
  const f32x4 z4 = {0.f, 0.f, 0.f, 0.f};
#pragma unroll
  for (int m = 0; m < 4; ++m)
#pragma unroll
    for (int n = 0; n < 4; ++n) acc[m][n] = z4;

  STG(0); STG(1); STG(2);
  asm volatile("s_waitcnt vmcnt(8)" ::: "memory");
  __builtin_amdgcn_s_barrier();
  __builtin_amdgcn_sched_barrier(0);

  const int kT = 32;
  for (int t = 0; t < kT; ++t) {
    if (t + 3 < kT) STG(t + 3);
    const char* bufp = smem + ((t & 3) << 14);
    bf16x8 af[4], bg[4];
#pragma unroll
    for (int m = 0; m < 4; ++m)
      af[m] = *(const bf16x8*)(bufp + rdA + (m << 10));
#pragma unroll
    for (int n = 0; n < 4; ++n)
      bg[n] = *(const bf16x8*)(bufp + rdB + (n << 10));
    __builtin_amdgcn_s_setprio(1);
#pragma unroll
    for (int m = 0; m < 4; ++m)
#pragma unroll
      for (int n = 0; n < 4; ++n)
        acc[m][n] = __builtin_amdgcn_mfma_f32_16x16x32_bf16(af[m], bg[n],
                                                            acc[m][n], 0, 0, 0);
    __builtin_amdgcn_s_setprio(0);
    __builtin_amdgcn_sched_barrier(0);
    if (t + 3 < kT)       asm volatile("s_waitcnt vmcnt(8)" ::: "memory");
    else if (t + 3 == kT) asm volatile("s_waitcnt vmcnt(4)" ::: "memory");
    else if (t + 2 == kT) asm volatile("s_waitcnt vmcnt(0)" ::: "memory");
    if (t + 1 < kT) {
      __builtin_amdgcn_s_barrier();
      __builtin_amdgcn_sched_barrier(0);
      asm volatile("" ::: "memory");
    }
  }
#undef STG

  const int rl0 = (wr << 6) + (l4 << 2);
  const int cl0 = (wc << 6) + l15;
  char* Ct = scoresBase + (long)bz * BATCH_B + (long)t0 * TILE_B;
  __syncthreads();
#pragma unroll
  for (int m = 0; m < 4; ++m)
#pragma unroll
    for (int r = 0; r < 4; ++r) {
      const int ql = rl0 + m * 16 + r;
      const int qg = bm * 128 + ql;
#pragma unroll
      for (int n = 0; n < 4; ++n) {
        const int kg = bn * 128 + cl0 + n * 16;
        const float v = (kg <= qg) ? acc[m][n][r] * 0.03125f : -1.0e9f;
        const int colx = (cl0 + n * 16) ^ (l4 << 4);
        *(unsigned short*)(smem + ql * 256 + colx * 2) = f2bf(v);
      }
    }
  __syncthreads();
#pragma unroll
  for (int i = 0; i < 8; ++i) {
    const int s2 = i * 256 + tid;
    const int row = s2 >> 4;
    const int cb = s2 & 15;
    const int lb = row * 256 + ((cb << 4) ^ (((row >> 2) & 3) << 5));
    *(uint4*)(Ct + (long)row * 256 + (cb << 4)) = *(const uint4*)(smem + lb);
  }
}

// ------------- softmax over compact causal prefix, bf16 128-tiles -----------
__global__ __launch_bounds__(256) void softmax_tri(char* __restrict__ base,
                                                   const int* __restrict__ nv) {
  const int r = blockIdx.x;
  const int bz = blockIdx.y;
  if (r >= nv[bz]) return;
  const int bm = r >> 7;
  const int w = (bm + 1) << 7;
  char* bb = base + (long)bz * BATCH_B +
             (long)(bm * (bm + 1) / 2) * TILE_B + (long)(r & 127) * 256;
  const int t = threadIdx.x;
  const bool act = (t << 3) < w;
  const int bn = t >> 4;
  const int cl = (t << 3) & 127;
  char* slot = bb + (long)bn * TILE_B + (long)cl * 2;
  float v[8];
  float m = -3.0e38f;
  if (act) {
    ushort4 u0 = ((const ushort4*)slot)[0];
    ushort4 u1 = ((const ushort4*)slot)[1];
    v[0] = bf2f(u0.x); v[1] = bf2f(u0.y); v[2] = bf2f(u0.z); v[3] = bf2f(u0.w);
    v[4] = bf2f(u1.x); v[5] = bf2f(u1.y); v[6] = bf2f(u1.z); v[7] = bf2f(u1.w);
#pragma unroll
    for (int k = 0; k < 8; ++k) m = fmaxf(m, v[k]);
  }
  __shared__ float red[8];
#pragma unroll
  for (int off = 32; off > 0; off >>= 1) m = fmaxf(m, __shfl_down(m, off, 64));
  const int wid = t >> 6, lane = t & 63;
  if (lane == 0) red[wid] = m;
  __syncthreads();
  m = fmaxf(fmaxf(red[0], red[1]), fmaxf(red[2], red[3]));
  float e[8];
  float s = 0.f;
  if (act) {
#pragma unroll
    for (int k = 0; k < 8; ++k) { e[k] = __expf(v[k] - m); s += e[k]; }
  }
#pragma unroll
  for (int off = 32; off > 0; off >>= 1) s += __shfl_down(s, off, 64);
  if (lane == 0) red[4 + wid] = s;
  __syncthreads();
  s = red[4] + red[5] + red[6] + red[7];
  const float inv = 1.0f / s;
  if (act) {
    ushort4 o0, o1;
    o0.x = f2bf(e[0] * inv); o0.y = f2bf(e[1] * inv);
    o0.z = f2bf(e[2] * inv); o0.w = f2bf(e[3] * inv);
    o1.x = f2bf(e[4] * inv); o1.y = f2bf(e[5] * inv);
    o1.z = f2bf(e[6] * inv); o1.w = f2bf(e[7] * inv);
    ((ushort4*)slot)[0] = o0;
    ((ushort4*)slot)[1] = o1;
  }
}

// -------- 128x128 ring-4 core: PV in compact space, scatter output ----------
__global__ __launch_bounds__(256, 2) void gemm_pv(
    const char* __restrict__ attn, const unsigned short* __restrict__ Vtc,
    float* __restrict__ Out, const int* __restrict__ vidx,
    const int* __restrict__ nv) {
  __shared__ __align__(16) char smem[65536];
  const int tid = threadIdx.x;
  const int wave = tid >> 6, lane = tid & 63;
  const int wr = wave >> 1, wc = wave & 1;
  const int l15 = lane & 15, l4 = lane >> 4;
  const int bz = blockIdx.z;
  const int bm = 15 - blockIdx.x;
  const int bn = blockIdx.y;

  const int nvb = nv[bz];
  const int nt = (nvb + 127) >> 7;
  if (bm >= nt) return;

  const char* Ab = attn + (long)bz * BATCH_B + (long)(bm * (bm + 1) / 2) * TILE_B;
  const unsigned short* B = Vtc + (long)bz * SS * HH;

  const int s0 = tid, s1 = tid + 256;
  const int rA0 = ((s0 >> 3) << 1) | (((s0 >> 2) & 1) ^ ((s0 >> 4) & 1));
  const int cA0 = (s0 & 3) ^ (rA0 & 3);
  const int rA1 = ((s1 >> 3) << 1) | (((s1 >> 2) & 1) ^ ((s1 >> 4) & 1));
  const int cA1 = (s1 & 3) ^ (rA1 & 3);
  const char* aB0 = Ab + (long)rA0 * 256 + cA0 * 16;
  const char* aB1 = Ab + (long)rA1 * 256 + cA1 * 16;
  const char* bG0 = (const char*)(B + (long)(bn * 128 + rA0) * SS) + cA0 * 16;
  const char* bG1 = (const char*)(B + (long)(bn * 128 + rA1) * SS) + cA1 * 16;
  const int ldsL0 = wave << 10;
  const int ldsL1 = 4096 + (wave << 10);

#define STGPV(t_) do { \
    char* _p = smem + (((t_) & 3) << 14); \
    const long _aO = (long)((t_) >> 2) * TILE_B + (long)((t_) & 3) * 64; \
    const long _bO = (long)(t_) << 6; \
    gl_lds16(aB0 + _aO, _p + ldsL0); \
    gl_lds16(aB1 + _aO, _p + ldsL1); \
    gl_lds16(bG0 + _bO, _p + 8192 + ldsL0); \
    gl_lds16(bG1 + _bO, _p + 8192 + ldsL1); } while (0)

  const int baseSwz = ((l15 * 64 + (l4 << 4)) ^ ((l15 & 7) << 4));
  const int rdA = (wr << 12) + baseSwz;
  const int rdB = 8192 + (wc << 12) + baseSwz;

  f32x4 acc[4][4];
  const f32x4 z4 = {0.f, 0.f, 0.f, 0.f};
#pragma unroll
  for (int m = 0; m < 4; ++m)
#pragma unroll
    for (int n = 0; n < 4; ++n) acc[m][n] = z4;

  STGPV(0); STGPV(1); STGPV(2);
  asm volatile("s_waitcnt vmcnt(8)" ::: "memory");
  __builtin_amdgcn_s_barrier();
  __builtin_amdgcn_sched_barrier(0);

  const int kT = (bm + 1) * 4;
  for (int t = 0; t < kT; ++t) {
    if (t + 3 < kT) STGPV(t + 3);
    const char* bufp = smem + ((t & 3) << 14);
    bf16x8 af[4], bg[4];
#pragma unroll
    for (int m = 0; m < 4; ++m)
      af[m] = *(const bf16x8*)(bufp + rdA + (m << 10));
#pragma unroll
    for (int n = 0; n < 4; ++n)
      bg[n] = *(const bf16x8*)(bufp + rdB + (n << 10));
    __builtin_amdgcn_s_setprio(1);
#pragma unroll
    for (int m = 0; m < 4; ++m)
#pragma unroll
      for (int n = 0; n < 4; ++n)
        acc[m][n] = __builtin_amdgcn_mfma_f32_16x16x32_bf16(af[m], bg[n],
                                                            acc[m][n], 0, 0, 0);
    __builtin_amdgcn_s_setprio(0);
    __builtin_amdgcn_sched_barrier(0);
    if (t + 3 < kT)       asm volatile("s_waitcnt vmcnt(8)" ::: "memory");
    else if (t + 3 == kT) asm volatile("s_waitcnt vmcnt(4)" ::: "memory");
    else if (t + 2 == kT) asm volatile("s_waitcnt vmcnt(0)" ::: "memory");
    if (t + 1 < kT) {
      __builtin_amdgcn_s_barrier();
      __builtin_amdgcn_sched_barrier(0);
      asm volatile("" ::: "memory");
    }
  }
#undef STGPV

  const int rl0 = (wr << 6) + (l4 << 2);
  const int cl0 = (wc << 6) + l15;
  __syncthreads();
#pragma unroll
  for (int m = 0; m < 4; ++m)
#pragma unroll
    for (int r = 0; r < 4; ++r) {
      const int ql = rl0 + m * 16 + r;
#pragma unroll
      for (int n = 0; n < 4; ++n) {
        const int colx = (cl0 + n * 16) ^ (l4 << 4);
        *(float*)(smem + ql * 512 + colx * 4) = acc[m][n][r];
      }
    }
  __syncthreads();
  const int* vb = vidx + (long)bz * SS;
#pragma unroll
  for (int i = 0; i < 16; ++i) {
    const int s2 = i * 256 + tid;
    const int row = s2 >> 5;
    const int cb = s2 & 31;
    const int lb = (row * 512 + (cb << 4)) ^ (((row >> 2) & 3) << 6);
    const int crow = bm * 128 + row;
    if (crow < nvb) {
      const int orig = vb[crow];
      *(uint4*)((char*)Out + (((long)bz * SS + orig) * HH) * 4 +
                (long)bn * 512 + (cb << 4)) = *(const uint4*)(smem + lb);
    }
  }
}

extern "C" void kernel_launch(void* const* d_in, const int* in_sizes, int n_in,
                              void* d_out, int out_size, void* d_ws, size_t ws_size,
                              hipStream_t stream) {
  (void)in_sizes; (void)n_in; (void)out_size; (void)ws_size;
  const float* x = (const float*)d_in[0];
  const unsigned char* mask_raw = (const unsigned char*)d_in[1];
  const float* Wq = (const float*)d_in[2];
  const float* bq = (const float*)d_in[3];
  const float* Wk = (const float*)d_in[4];
  const float* bk = (const float*)d_in[5];
  const float* Wv = (const float*)d_in[6];
  const float* bv = (const float*)d_in[7];
  char* ws = (char*)d_ws;

  unsigned short* Xbf = (unsigned short*)(ws + OFF_XBF);
  unsigned short* Wbf = (unsigned short*)(ws + OFF_WBF);
  unsigned short* Qc = (unsigned short*)(ws + OFF_Q);
  unsigned short* Kc = (unsigned short*)(ws + OFF_K);
  unsigned short* Vt = (unsigned short*)(ws + OFF_VT);
  unsigned short* Vtc = (unsigned short*)(ws + OFF_VTC);
  unsigned char* mask = (unsigned char*)(ws + OFF_MASK);
  float* meanV = (float*)(ws + OFF_MEANV);
  int* vidx = (int*)(ws + OFF_VIDX);
  int* nv = (int*)(ws + OFF_NV);

  const long MS = (long)BB * SS;  // 16384

  (void)hipFuncSetAttribute((const void*)gemm256,
                            hipFuncAttributeMaxDynamicSharedMemorySize, 131072);

  // 0. mask canonicalize -> compaction table; zero meanV
  canon_mask<<<1, 1024, 0, stream>>>(mask_raw, mask);
  build_compact<<<BB, 256, 0, stream>>>(mask, vidx, nv);
  hipMemsetAsync(meanV, 0, (size_t)BB * HH * 4, stream);

  // 1. fp32 -> bf16
  cvt_f32_bf16<<<2048, 256, 0, stream>>>(x, Xbf, (int)(MS * HH / 4));
  cvt_w3<<<dim3(256, 3), 256, 0, stream>>>(Wq, Wk, Wv, Wbf);

  // 2. fused QKV: grid (192,4), z FASTEST in x (load-balance interleave).
  //    Q/K M-compacted; V full -> Vt + meanV sums.
  gemm256<<<dim3((MS / 256) * 3, HH / 256), 512, 131072, stream>>>(
      Xbf, Wbf, (long)HH * HH,
      (char*)Qc, (char*)Kc, (char*)Vt, bq, bk, bv, meanV, vidx, nv);

  // 3. compact V columns: Vtc[h][j] = Vt[h][vidx[j]]
  vtc_gather<<<dim3(HH, BB), 256, 0, stream>>>(Vt, vidx, nv, Vtc);

  // 4. scores in compact space (pure triangular)
  gemm128s<<<dim3(NTRI, BB), 256, 0, stream>>>(
      Qc, Kc, ws + OFF_SCORES, nv);

  // 5. softmax over compact causal prefix (rows < nv only)
  softmax_tri<<<dim3(SS, BB), 256, 0, stream>>>(ws + OFF_SCORES, nv);

  // 6. PV in compact space; scatter rows to original positions
  gemm_pv<<<dim3(SS / 128, HH / 128, BB), 256, 0, stream>>>(
      ws + OFF_SCORES, Vtc, (float*)d_out, vidx, nv);

  // 7. masked query rows -> uniform mean of V
  fixup_masked<<<BB * SS, 256, 0, stream>>>((float*)d_out, mask, meanV);
}

// Round 16
// 246.020 us; speedup vs baseline: 1.0729x; 1.0729x over previous
//
#include <hip/hip_runtime.h>
#include <stdint.h>

typedef __bf16 bf16x8 __attribute__((ext_vector_type(8)));
typedef float f32x4 __attribute__((ext_vector_type(4)));

#define BB 8
#define SS 2048
#define HH 1024

// compact triangular scores: 128x128 tiles in COMPACTED key/query space.
#define TILE_B   32768ll
#define NTRI     136
#define BATCH_B  (NTRI * TILE_B)

// ws layout (bytes). Peak ~140 MiB.
#define OFF_Q      0ll
#define OFF_K      33554432ll
#define OFF_VTC    67108864ll    // compact Vt (written directly by gemm256q)
#define OFF_MASK   100663296ll
#define OFF_MEANV  100679680ll
#define OFF_VIDX   100712448ll
#define OFF_NV     100777984ll
#define OFF_XSUM   100778048ll   // fp32[8][1024]
#define OFF_QCTL   100843520ll   // int[2]: head, tail
#define OFF_QUEUE  100843584ll   // int[768]
#define OFF_TMP    101711872ll
#define OFF_XBF    (OFF_TMP)
#define OFF_WBF    (OFF_TMP + 33554432ll)
#define OFF_SCORES (OFF_TMP + 39845888ll)

__device__ __forceinline__ unsigned short f2bf(float f) {
  unsigned int u = __float_as_uint(f);
  u += 0x7FFFu + ((u >> 16) & 1u);   // RTNE
  return (unsigned short)(u >> 16);
}
__device__ __forceinline__ float bf2f(unsigned short u) {
  return __uint_as_float(((unsigned int)u) << 16);
}

__device__ __forceinline__ void gl_lds16(const void* g, void* l) {
  __builtin_amdgcn_global_load_lds(
      (const __attribute__((address_space(1))) void*)g,
      (__attribute__((address_space(3))) void*)l, 16, 0, 0);
}

// ------- mask canonicalizer (uint8 / int32 / float32), 1024-thr vectorized --
__global__ __launch_bounds__(1024) void canon_mask(
    const unsigned char* __restrict__ m, unsigned char* __restrict__ out) {
  __shared__ int cnt[4];
  const int t = threadIdx.x;
  if (t < 4) cnt[t] = 0;
  __syncthreads();
  uint4 v = ((const uint4*)m)[t];
  const unsigned char* pb = (const unsigned char*)&v;
  int loc[4] = {0, 0, 0, 0};
#pragma unroll
  for (int j = 0; j < 16; ++j)
    if (pb[j]) loc[j & 3]++;
#pragma unroll
  for (int r = 0; r < 4; ++r)
    if (loc[r]) atomicAdd(&cnt[r], loc[r]);
  __syncthreads();
  const int c0 = cnt[0], c1 = cnt[1], c2 = cnt[2], c3 = cnt[3];
  unsigned char ob[16];
  if (c0 > 0 && c1 == 0 && c2 == 0 && c3 == 0) {        // int32 0/1
    const int* mi = (const int*)m;
#pragma unroll
    for (int j = 0; j < 16; ++j) ob[j] = mi[t * 16 + j] ? 1 : 0;
  } else if (c0 == 0 && (c2 > 0 || c3 > 0)) {           // float32
    const float* mf = (const float*)m;
#pragma unroll
    for (int j = 0; j < 16; ++j) ob[j] = (mf[t * 16 + j] != 0.0f) ? 1 : 0;
  } else {                                              // uint8 bool
#pragma unroll
    for (int j = 0; j < 16; ++j) ob[j] = pb[j] ? 1 : 0;
  }
  ((uint4*)out)[t] = *(const uint4*)ob;
}

// ------- per-batch compaction: vidx, nv, and ACTIVE-TILE work queue ---------
// queue entry: (bm<<4)|(z<<2)|bn, bm = b*8 + tileInBatch (256-row tiles)
__global__ __launch_bounds__(256) void build_compact(
    const unsigned char* __restrict__ mask, int* __restrict__ vidx,
    int* __restrict__ nv, int* __restrict__ qctl, int* __restrict__ queue) {
  const int b = blockIdx.x;
  const int t = threadIdx.x;
  __shared__ int cnt[256];
  __shared__ int totalS;
  const unsigned char* mb = mask + b * SS;
  unsigned char m[8];
  int c = 0;
#pragma unroll
  for (int j = 0; j < 8; ++j) { m[j] = mb[t * 8 + j]; c += m[j] ? 1 : 0; }
  cnt[t] = c;
  __syncthreads();
  int base = 0;
  for (int i = 0; i < t; ++i) base += cnt[i];
  if (t == 255) totalS = base + c;
  int pos = base;
  int* vb = vidx + b * SS;
#pragma unroll
  for (int j = 0; j < 8; ++j) {
    const int s = t * 8 + j;
    if (m[j]) { vb[pos] = s; ++pos; }
  }
  __syncthreads();
  const int total = totalS;
  if (t == 0) {
    nv[b] = total;
    const int ntile = (total + 255) >> 8;
    const int n = ntile * 12;
    const int qb = atomicAdd(&qctl[1], n);
    int k = 0;
    for (int tt = 0; tt < ntile; ++tt)
      for (int z = 0; z < 3; ++z)
        for (int bn = 0; bn < 4; ++bn)
          queue[qb + (k++)] = (((b << 3) | tt) << 4) | (z << 2) | bn;
  }
  for (int idx = total + t; idx < SS; idx += 256) vb[idx] = 0;
}

__global__ void cvt_f32_bf16(const float* __restrict__ in,
                             unsigned short* __restrict__ out, int n4) {
  int i = blockIdx.x * blockDim.x + threadIdx.x;
  int stride = gridDim.x * blockDim.x;
  for (; i < n4; i += stride) {
    float4 v = ((const float4*)in)[i];
    ushort4 o;
    o.x = f2bf(v.x); o.y = f2bf(v.y); o.z = f2bf(v.z); o.w = f2bf(v.w);
    ((ushort4*)out)[i] = o;
  }
}

__global__ void cvt_w3(const float* __restrict__ Wq, const float* __restrict__ Wk,
                       const float* __restrict__ Wv, unsigned short* __restrict__ out) {
  const int z = blockIdx.y;
  const float* src = (z == 0) ? Wq : (z == 1) ? Wk : Wv;
  unsigned short* dst = out + (long)z * (HH * HH);
  const int n4 = HH * HH / 4;
  int i = blockIdx.x * 256 + threadIdx.x;
  for (; i < n4; i += 256 * 256) {
    float4 v = ((const float4*)src)[i];
    ushort4 o;
    o.x = f2bf(v.x); o.y = f2bf(v.y); o.z = f2bf(v.z); o.w = f2bf(v.w);
    ((ushort4*)dst)[i] = o;
  }
}

// ------- per-batch column sums of Xbf (for meanV): xsum pre-zeroed ----------
__global__ __launch_bounds__(256) void xsum_cols(
    const unsigned short* __restrict__ Xbf, float* __restrict__ xsum) {
  const int b = blockIdx.y;
  const int sc = blockIdx.x;        // 32 chunks of 64 rows
  const int t = threadIdx.x;        // col group t*4
  const unsigned short* base = Xbf + ((long)b * SS + sc * 64) * HH + t * 4;
  float s0 = 0.f, s1 = 0.f, s2 = 0.f, s3 = 0.f;
#pragma unroll 4
  for (int i = 0; i < 64; ++i) {
    ushort4 u = *(const ushort4*)(base + (long)i * HH);
    s0 += bf2f(u.x); s1 += bf2f(u.y); s2 += bf2f(u.z); s3 += bf2f(u.w);
  }
  float* xs = xsum + b * HH + t * 4;
  atomicAdd(&xs[0], s0); atomicAdd(&xs[1], s1);
  atomicAdd(&xs[2], s2); atomicAdd(&xs[3], s3);
}

// ------- meanV[b][h] = dot(xsum[b], Wv[h]) + 2048*bv[h] ---------------------
__global__ __launch_bounds__(256) void meanv_dot(
    const float* __restrict__ xsum, const unsigned short* __restrict__ Wvbf,
    const float* __restrict__ bv, float* __restrict__ meanV) {
  const int b = blockIdx.y;
  const int wave = threadIdx.x >> 6, lane = threadIdx.x & 63;
  const int h = blockIdx.x * 4 + wave;
  const unsigned short* wrow = Wvbf + (long)h * HH + lane * 16;
  const float* xs = xsum + b * HH + lane * 16;
  float s = 0.f;
#pragma unroll
  for (int j = 0; j < 4; ++j) {
    ushort4 u = *(const ushort4*)(wrow + j * 4);
    s += bf2f(u.x) * xs[j * 4 + 0] + bf2f(u.y) * xs[j * 4 + 1] +
         bf2f(u.z) * xs[j * 4 + 2] + bf2f(u.w) * xs[j * 4 + 3];
  }
#pragma unroll
  for (int off = 32; off > 0; off >>= 1) s += __shfl_down(s, off, 64);
  if (lane == 0) meanV[(long)b * HH + h] = s + 2048.0f * bv[h];
}

// masked query rows -> uniform mean of V
__global__ __launch_bounds__(256) void fixup_masked(
    float* __restrict__ out, const unsigned char* __restrict__ mask,
    const float* __restrict__ sums) {
  const long row = blockIdx.x;
  if (mask[row]) return;
  const long b = row >> 11;
  const int t = threadIdx.x;
  float4 v = ((const float4*)(sums + b * HH))[t];
  v.x *= (1.f / 2048.f); v.y *= (1.f / 2048.f);
  v.z *= (1.f / 2048.f); v.w *= (1.f / 2048.f);
  ((float4*)(out + row * HH))[t] = v;
}

// ===== 256x256 fused QKV — WORK-QUEUE 8-phase core, all-M-compact ===========
// 256 blocks (1/CU) pop active (bm,z,bn) entries from the queue: true dynamic
// load balance (static round-robin CU assignment defeated r14/r15 early-exit).
// All thirds gather A rows through vidx; z==2 writes compact Vtc directly.
__global__ __launch_bounds__(512, 2) void gemm256q(
    const unsigned short* __restrict__ Abase,
    const unsigned short* __restrict__ Bbase, long bStride,
    char* __restrict__ Cq, char* __restrict__ Ck, char* __restrict__ VtcOut,
    const float* __restrict__ biasq, const float* __restrict__ biask,
    const float* __restrict__ biasv,
    const int* __restrict__ vidx, const int* __restrict__ queue,
    int* __restrict__ qctl) {
  extern __shared__ char smem[];
  int* bc = (int*)(smem + 131072);
  const int tid = threadIdx.x;
  const int wave = tid >> 6, lane = tid & 63;
  const int wr = wave >> 2, wc = wave & 3;
  const int l15 = lane & 15, l4 = lane >> 4;

  const int srow = tid >> 3;
  const int gslot = (tid & 7) ^ (srow & 7);
  const int ldsStageW = wave << 10;
  const int sw0 = ((l4 ^ (l15 & 7)) << 4);
  const int sw1 = (((4 + l4) ^ (l15 & 7)) << 4);
  const int aB0 = (wr << 14) + l15 * 128 + sw0;
  const int aB1 = (wr << 14) + l15 * 128 + sw1;
  const int bB0 = 32768 + ((wc >> 1) << 14) + (((wc & 1) << 6) + l15) * 128 + sw0;
  const int bB1 = 32768 + ((wc >> 1) << 14) + (((wc & 1) << 6) + l15) * 128 + sw1;
  const int rl0 = (wr << 7) + (l4 << 2);
  const int cl0 = (wc << 6) + l15;
  const int qcnt = qctl[1];

  for (;;) {
    __syncthreads();                       // LDS WAR: prev epilogue reads done
    if (tid == 0) *bc = atomicAdd(&qctl[0], 1);
    __syncthreads();
    const int idx = *bc;
    if (idx >= qcnt) break;
    const int e = queue[idx];
    const int bm = e >> 4;
    const int bz = (e >> 2) & 3;
    const int bn = e & 3;
    const int b = bm >> 3;
    const int rInB = (bm & 7) * 256;

    const int* vb = vidx + b * SS;
    const char* aS[4];
#pragma unroll
    for (int j = 0; j < 4; ++j) {
      const int r = rInB + srow + 64 * j;
      aS[j] = (const char*)Abase + ((long)b * SS + vb[r]) * 2048 + gslot * 16;
    }
    const char* gB = (const char*)(Bbase + (long)bz * bStride) +
                     ((long)bn * 256 + srow) * 2048 + gslot * 16;

#define STG(kt_, type_, buf_) do { \
    char* _l = smem + ((buf_) << 16) + (((type_) >> 1) << 15) + \
               (((type_) & 1) << 14) + ldsStageW; \
    if ((type_) < 2) { \
      gl_lds16(aS[(type_) * 2]     + ((long)(kt_) << 7), _l); \
      gl_lds16(aS[(type_) * 2 + 1] + ((long)(kt_) << 7), _l + 8192); \
    } else { \
      const char* _g = gB + (((type_) & 1) ? 262144 : 0) + ((long)(kt_) << 7); \
      gl_lds16(_g, _l); \
      gl_lds16(_g + 131072, _l + 8192); \
    } } while (0)

    f32x4 acc[8][4];
    const f32x4 z4 = {0.f, 0.f, 0.f, 0.f};
#pragma unroll
    for (int m = 0; m < 8; ++m)
#pragma unroll
      for (int n = 0; n < 4; ++n) acc[m][n] = z4;

    STG(0, 0, 0); STG(0, 1, 0); STG(0, 2, 0); STG(0, 3, 0);
    STG(1, 0, 1); STG(1, 1, 1); STG(1, 2, 1); STG(1, 3, 1);
    asm volatile("s_waitcnt vmcnt(8)" ::: "memory");
    __builtin_amdgcn_s_barrier();
    __builtin_amdgcn_sched_barrier(0);

    bf16x8 aC[4][2], bLo[2][2], bHi[2][2];

    for (int it = 0; it < 8; ++it) {
#pragma unroll
      for (int g = 0; g < 8; ++g) {
        const int buf = (g < 4) ? 0 : 65536;
        const int q = g & 3;
        if (q == 0) {
#pragma unroll
          for (int mm = 0; mm < 4; ++mm) {
            aC[mm][0] = *(const bf16x8*)(smem + buf + aB0 + mm * 2048);
            aC[mm][1] = *(const bf16x8*)(smem + buf + aB1 + mm * 2048);
          }
#pragma unroll
          for (int nn = 0; nn < 2; ++nn) {
            bLo[nn][0] = *(const bf16x8*)(smem + buf + bB0 + nn * 2048);
            bLo[nn][1] = *(const bf16x8*)(smem + buf + bB1 + nn * 2048);
          }
        } else if (q == 1) {
#pragma unroll
          for (int nn = 0; nn < 2; ++nn) {
            bHi[nn][0] = *(const bf16x8*)(smem + buf + bB0 + (2 + nn) * 2048);
            bHi[nn][1] = *(const bf16x8*)(smem + buf + bB1 + (2 + nn) * 2048);
          }
        } else if (q == 2) {
#pragma unroll
          for (int mm = 0; mm < 4; ++mm) {
            aC[mm][0] = *(const bf16x8*)(smem + buf + aB0 + (4 + mm) * 2048);
            aC[mm][1] = *(const bf16x8*)(smem + buf + aB1 + (4 + mm) * 2048);
          }
        }
        {
          const int u = it * 8 + g - 2;
          if (u >= 0) {
            const int kt = 2 + (u >> 2);
            if (kt < 16) {
              if (g == 0)      STG(kt, 0, 1);
              else if (g == 1) STG(kt, 1, 1);
              else if (g == 2) STG(kt, 2, 0);
              else if (g == 3) STG(kt, 3, 0);
              else if (g == 4) STG(kt, 0, 0);
              else if (g == 5) STG(kt, 1, 0);
              else if (g == 6) STG(kt, 2, 1);
              else             STG(kt, 3, 1);
            }
          }
        }
        __builtin_amdgcn_s_barrier();
        asm volatile("s_waitcnt lgkmcnt(0)" ::: "memory");
        __builtin_amdgcn_sched_barrier(0);
        __builtin_amdgcn_s_setprio(1);
        if (q == 0) {
#pragma unroll
          for (int mm = 0; mm < 4; ++mm)
#pragma unroll
            for (int nn = 0; nn < 2; ++nn) {
              acc[mm][nn] = __builtin_amdgcn_mfma_f32_16x16x32_bf16(
                  aC[mm][0], bLo[nn][0], acc[mm][nn], 0, 0, 0);
              acc[mm][nn] = __builtin_amdgcn_mfma_f32_16x16x32_bf16(
                  aC[mm][1], bLo[nn][1], acc[mm][nn], 0, 0, 0);
            }
        } else if (q == 1) {
#pragma unroll
          for (int mm = 0; mm < 4; ++mm)
#pragma unroll
            for (int nn = 0; nn < 2; ++nn) {
              acc[mm][2 + nn] = __builtin_amdgcn_mfma_f32_16x16x32_bf16(
                  aC[mm][0], bHi[nn][0], acc[mm][2 + nn], 0, 0, 0);
              acc[mm][2 + nn] = __builtin_amdgcn_mfma_f32_16x16x32_bf16(
                  aC[mm][1], bHi[nn][1], acc[mm][2 + nn], 0, 0, 0);
            }
        } else if (q == 2) {
#pragma unroll
          for (int mm = 0; mm < 4; ++mm)
#pragma unroll
            for (int nn = 0; nn < 2; ++nn) {
              acc[4 + mm][2 + nn] = __builtin_amdgcn_mfma_f32_16x16x32_bf16(
                  aC[mm][0], bHi[nn][0], acc[4 + mm][2 + nn], 0, 0, 0);
              acc[4 + mm][2 + nn] = __builtin_amdgcn_mfma_f32_16x16x32_bf16(
                  aC[mm][1], bHi[nn][1], acc[4 + mm][2 + nn], 0, 0, 0);
            }
        } else {
#pragma unroll
          for (int mm = 0; mm < 4; ++mm)
#pragma unroll
            for (int nn = 0; nn < 2; ++nn) {
              acc[4 + mm][nn] = __builtin_amdgcn_mfma_f32_16x16x32_bf16(
                  aC[mm][0], bLo[nn][0], acc[4 + mm][nn], 0, 0, 0);
              acc[4 + mm][nn] = __builtin_amdgcn_mfma_f32_16x16x32_bf16(
                  aC[mm][1], bLo[nn][1], acc[4 + mm][nn], 0, 0, 0);
            }
        }
        __builtin_amdgcn_s_setprio(0);
        __builtin_amdgcn_sched_barrier(0);
        if (q == 3) {
          if (g == 3 && it == 7)
            asm volatile("s_waitcnt vmcnt(0)" ::: "memory");
          else
            asm volatile("s_waitcnt vmcnt(4)" ::: "memory");
        }
        __builtin_amdgcn_s_barrier();
        asm volatile("" ::: "memory");
      }
    }
#undef STG

    if (bz < 2) {
      // ---- row-major bounce; contiguous compact write ----
      const float* bias = (bz == 0) ? biasq : biask;
#pragma unroll
      for (int n = 0; n < 4; ++n) {
        const int cl = cl0 + n * 16;
        const float bv = bias[bn * 256 + cl];
        const int colx = cl ^ (l4 << 4);
#pragma unroll
        for (int m = 0; m < 8; ++m) {
          const int rl = rl0 + m * 16;
#pragma unroll
          for (int r = 0; r < 4; ++r)
            *(unsigned short*)(smem + (rl + r) * 512 + colx * 2) =
                f2bf(acc[m][n][r] + bv);
        }
      }
      __syncthreads();
      unsigned short* C = (unsigned short*)((bz == 0) ? Cq : Ck);
      const long rowg0 = (long)b * SS + rInB;
      const long colb0 = (long)bn * 512;
#pragma unroll
      for (int i = 0; i < 16; ++i) {
        const int s2 = i * 512 + tid;
        const int row = s2 >> 5;
        const int cb = s2 & 31;
        const int lb = (row * 512 + (cb << 4)) ^ (((row >> 2) & 3) << 5);
        *(uint4*)((char*)C + (rowg0 + row) * 2048 + colb0 + (cb << 4)) =
            *(const uint4*)(smem + lb);
      }
    } else {
      // ---- WRITE-side transposed bounce -> compact Vtc ----
#pragma unroll
      for (int n = 0; n < 4; ++n) {
        const int h = cl0 + n * 16;
        const float bv = biasv[bn * 256 + h];
        const int xr = (h & 7) << 4;
#pragma unroll
        for (int m = 0; m < 8; ++m) {
          const int s0a = rl0 + m * 16;
          uint2 w;
          w.x = (unsigned)f2bf(acc[m][n][0] + bv) |
                ((unsigned)f2bf(acc[m][n][1] + bv) << 16);
          w.y = (unsigned)f2bf(acc[m][n][2] + bv) |
                ((unsigned)f2bf(acc[m][n][3] + bv) << 16);
          *(uint2*)(smem + h * 512 + ((s0a * 2) ^ xr)) = w;
        }
      }
      __syncthreads();
      char* VtB = VtcOut + (long)b * (SS * HH * 2) + (long)(bm & 7) * 512;
#pragma unroll
      for (int i = 0; i < 16; ++i) {
        const int s2 = i * 512 + tid;
        const int h = s2 >> 5;
        const int cb = s2 & 31;
        const int lb = h * 512 + ((cb << 4) ^ ((h & 7) << 4));
        *(uint4*)(VtB + (long)(bn * 256 + h) * 4096 + cb * 16) =
            *(const uint4*)(smem + lb);
      }
    }
  }
}

// -------- 128x128 ring-4 core: SCORES in compact space (pure triangular) ----
__global__ __launch_bounds__(256, 2) void gemm128s(
    const unsigned short* __restrict__ Qc, const unsigned short* __restrict__ Kc,
    char* __restrict__ scoresBase, const int* __restrict__ nv) {
  __shared__ __align__(16) char smem[65536];
  const int tid = threadIdx.x;
  const int wave = tid >> 6, lane = tid & 63;
  const int wr = wave >> 1, wc = wave & 1;
  const int l15 = lane & 15, l4 = lane >> 4;
  const int bz = blockIdx.y;

  int t0 = blockIdx.x, bm = 0, a_ = 0;
  while (a_ + bm + 1 <= t0) { ++bm; a_ += bm; }
  const int bn = t0 - a_;

  const int nt = (nv[bz] + 127) >> 7;
  if (bm >= nt) return;

  const unsigned short* A = Qc + (long)bz * SS * HH;
  const unsigned short* B = Kc + (long)bz * SS * HH;

  const int s0 = tid, s1 = tid + 256;
  const int rA0 = ((s0 >> 3) << 1) | (((s0 >> 2) & 1) ^ ((s0 >> 4) & 1));
  const int cA0 = (s0 & 3) ^ (rA0 & 3);
  const int rA1 = ((s1 >> 3) << 1) | (((s1 >> 2) & 1) ^ ((s1 >> 4) & 1));
  const int cA1 = (s1 & 3) ^ (rA1 & 3);
  const char* aG0 = (const char*)A + (long)(bm * 128 + rA0) * 2048 + cA0 * 16;
  const char* aG1 = (const char*)A + (long)(bm * 128 + rA1) * 2048 + cA1 * 16;
  const char* bG0 = (const char*)B + (long)(bn * 128 + rA0) * 2048 + cA0 * 16;
  const char* bG1 = (const char*)B + (long)(bn * 128 + rA1) * 2048 + cA1 * 16;
  const int ldsL0 = wave << 10;
  const int ldsL1 = 4096 + (wave << 10);

#define STG(t_) do { \
    char* _p = smem + (((t_) & 3) << 14); \
    const long _ko = (long)(t_) << 6; \
    gl_lds16(aG0 + _ko, _p + ldsL0); \
    gl_lds16(aG1 + _ko, _p + ldsL1); \
    gl_lds16(bG0 + _ko, _p + 8192 + ldsL0); \
    gl_lds16(bG1 + _ko, _p + 8192 + ldsL1); } while (0)

  const int baseSwz = ((l15 * 64 + (l4 << 4)) ^ ((l15 & 7) << 4));
  const int rdA = (wr << 12) + baseSwz;
  const int rdB = 8192 + (wc << 12) + baseSwz;

  f32x4 acc[4][4];
  const f32x4 z4 = {0.f, 0.f, 0.f, 0.f};
#pragma unroll
  for (int m = 0; m < 4; ++m)
#pragma unroll
    for (int n = 0; n < 4; ++n) acc[m][n] = z4;

  STG(0); STG(1); STG(2);
  asm volatile("s_waitcnt vmcnt(8)" ::: "memory");
  __builtin_amdgcn_s_barrier();
  __builtin_amdgcn_sched_barrier(0);

  const int kT = 32;
  for (int t = 0; t < kT; ++t) {
    if (t + 3 < kT) STG(t + 3);
    const char* bufp = smem + ((t & 3) << 14);
    bf16x8 af[4], bg[4];
#pragma unroll
    for (int m = 0; m < 4; ++m)
      af[m] = *(const bf16x8*)(bufp + rdA + (m << 10));
#pragma unroll
    for (int n = 0; n < 4; ++n)
      bg[n] = *(const bf16x8*)(bufp + rdB + (n << 10));
    __builtin_amdgcn_s_setprio(1);
#pragma unroll
    for (int m = 0; m < 4; ++m)
#pragma unroll
      for (int n = 0; n < 4; ++n)
        acc[m][n] = __builtin_amdgcn_mfma_f32_16x16x32_bf16(af[m], bg[n],
                                                            acc[m][n], 0, 0, 0);
    __builtin_amdgcn_s_setprio(0);
    __builtin_amdgcn_sched_barrier(0);
    if (t + 3 < kT)       asm volatile("s_waitcnt vmcnt(8)" ::: "memory");
    else if (t + 3 == kT) asm volatile("s_waitcnt vmcnt(4)" ::: "memory");
    else if (t + 2 == kT) asm volatile("s_waitcnt vmcnt(0)" ::: "memory");
    if (t + 1 < kT) {
      __builtin_amdgcn_s_barrier();
      __builtin_amdgcn_sched_barrier(0);
      asm volatile("" ::: "memory");
    }
  }
#undef STG

  const int rl0 = (wr << 6) + (l4 << 2);
  const int cl0 = (wc << 6) + l15;
  char* Ct = scoresBase + (long)bz * BATCH_B + (long)t0 * TILE_B;
  __syncthreads();
#pragma unroll
  for (int m = 0; m < 4; ++m)
#pragma unroll
    for (int r = 0; r < 4; ++r) {
      const int ql = rl0 + m * 16 + r;
      const int qg = bm * 128 + ql;
#pragma unroll
      for (int n = 0; n < 4; ++n) {
        const int kg = bn * 128 + cl0 + n * 16;
        const float v = (kg <= qg) ? acc[m][n][r] * 0.03125f : -1.0e9f;
        const int colx = (cl0 + n * 16) ^ (l4 << 4);
        *(unsigned short*)(smem + ql * 256 + colx * 2) = f2bf(v);
      }
    }
  __syncthreads();
#pragma unroll
  for (int i = 0; i < 8; ++i) {
    const int s2 = i * 256 + tid;
    const int row = s2 >> 4;
    const int cb = s2 & 15;
    const int lb = row * 256 + ((cb << 4) ^ (((row >> 2) & 3) << 5));
    *(uint4*)(Ct + (long)row * 256 + (cb << 4)) = *(const uint4*)(smem + lb);
  }
}

// ------------- softmax over compact causal prefix, bf16 128-tiles -----------
__global__ __launch_bounds__(256) void softmax_tri(char* __restrict__ base,
                                                   const int* __restrict__ nv) {
  const int r = blockIdx.x;
  const int bz = blockIdx.y;
  if (r >= nv[bz]) return;
  const int bm = r >> 7;
  const int w = (bm + 1) << 7;
  char* bb = base + (long)bz * BATCH_B +
             (long)(bm * (bm + 1) / 2) * TILE_B + (long)(r & 127) * 256;
  const int t = threadIdx.x;
  const bool act = (t << 3) < w;
  const int bn = t >> 4;
  const int cl = (t << 3) & 127;
  char* slot = bb + (long)bn * TILE_B + (long)cl * 2;
  float v[8];
  float m = -3.0e38f;
  if (act) {
    ushort4 u0 = ((const ushort4*)slot)[0];
    ushort4 u1 = ((const ushort4*)slot)[1];
    v[0] = bf2f(u0.x); v[1] = bf2f(u0.y); v[2] = bf2f(u0.z); v[3] = bf2f(u0.w);
    v[4] = bf2f(u1.x); v[5] = bf2f(u1.y); v[6] = bf2f(u1.z); v[7] = bf2f(u1.w);
#pragma unroll
    for (int k = 0; k < 8; ++k) m = fmaxf(m, v[k]);
  }
  __shared__ float red[8];
#pragma unroll
  for (int off = 32; off > 0; off >>= 1) m = fmaxf(m, __shfl_down(m, off, 64));
  const int wid = t >> 6, lane = t & 63;
  if (lane == 0) red[wid] = m;
  __syncthreads();
  m = fmaxf(fmaxf(red[0], red[1]), fmaxf(red[2], red[3]));
  float e[8];
  float s = 0.f;
  if (act) {
#pragma unroll
    for (int k = 0; k < 8; ++k) { e[k] = __expf(v[k] - m); s += e[k]; }
  }
#pragma unroll
  for (int off = 32; off > 0; off >>= 1) s += __shfl_down(s, off, 64);
  if (lane == 0) red[4 + wid] = s;
  __syncthreads();
  s = red[4] + red[5] + red[6] + red[7];
  const float inv = 1.0f / s;
  if (act) {
    ushort4 o0, o1;
    o0.x = f2bf(e[0] * inv); o0.y = f2bf(e[1] * inv);
    o0.z = f2bf(e[2] * inv); o0.w = f2bf(e[3] * inv);
    o1.x = f2bf(e[4] * inv); o1.y = f2bf(e[5] * inv);
    o1.z = f2bf(e[6] * inv); o1.w = f2bf(e[7] * inv);
    ((ushort4*)slot)[0] = o0;
    ((ushort4*)slot)[1] = o1;
  }
}

// -------- 128x128 ring-4 core: PV in compact space, scatter output ----------
__global__ __launch_bounds__(256, 2) void gemm_pv(
    const char* __restrict__ attn, const unsigned short* __restrict__ Vtc,
    float* __restrict__ Out, const int* __restrict__ vidx,
    const int* __restrict__ nv) {
  __shared__ __align__(16) char smem[65536];
  const int tid = threadIdx.x;
  const int wave = tid >> 6, lane = tid & 63;
  const int wr = wave >> 1, wc = wave & 1;
  const int l15 = lane & 15, l4 = lane >> 4;
  const int bz = blockIdx.z;
  const int bm = 15 - blockIdx.x;
  const int bn = blockIdx.y;

  const int nvb = nv[bz];
  const int nt = (nvb + 127) >> 7;
  if (bm >= nt) return;

  const char* Ab = attn + (long)bz * BATCH_B + (long)(bm * (bm + 1) / 2) * TILE_B;
  const unsigned short* B = Vtc + (long)bz * SS * HH;

  const int s0 = tid, s1 = tid + 256;
  const int rA0 = ((s0 >> 3) << 1) | (((s0 >> 2) & 1) ^ ((s0 >> 4) & 1));
  const int cA0 = (s0 & 3) ^ (rA0 & 3);
  const int rA1 = ((s1 >> 3) << 1) | (((s1 >> 2) & 1) ^ ((s1 >> 4) & 1));
  const int cA1 = (s1 & 3) ^ (rA1 & 3);
  const char* aB0 = Ab + (long)rA0 * 256 + cA0 * 16;
  const char* aB1 = Ab + (long)rA1 * 256 + cA1 * 16;
  const char* bG0 = (const char*)(B + (long)(bn * 128 + rA0) * SS) + cA0 * 16;
  const char* bG1 = (const char*)(B + (long)(bn * 128 + rA1) * SS) + cA1 * 16;
  const int ldsL0 = wave << 10;
  const int ldsL1 = 4096 + (wave << 10);

#define STGPV(t_) do { \
    char* _p = smem + (((t_) & 3) << 14); \
    const long _aO = (long)((t_) >> 2) * TILE_B + (long)((t_) & 3) * 64; \
    const long _bO = (long)(t_) << 6; \
    gl_lds16(aB0 + _aO, _p + ldsL0); \
    gl_lds16(aB1 + _aO, _p + ldsL1); \
    gl_lds16(bG0 + _bO, _p + 8192 + ldsL0); \
    gl_lds16(bG1 + _bO, _p + 8192 + ldsL1); } while (0)

  const int baseSwz = ((l15 * 64 + (l4 << 4)) ^ ((l15 & 7) << 4));
  const int rdA = (wr << 12) + baseSwz;
  const int rdB = 8192 + (wc << 12) + baseSwz;

  f32x4 acc[4][4];
  const f32x4 z4 = {0.f, 0.f, 0.f, 0.f};
#pragma unroll
  for (int m = 0; m < 4; ++m)
#pragma unroll
    for (int n = 0; n < 4; ++n) acc[m][n] = z4;

  STGPV(0); STGPV(1); STGPV(2);
  asm volatile("s_waitcnt vmcnt(8)" ::: "memory");
  __builtin_amdgcn_s_barrier();
  __builtin_amdgcn_sched_barrier(0);

  const int kT = (bm + 1) * 4;
  for (int t = 0; t < kT; ++t) {
    if (t + 3 < kT) STGPV(t + 3);
    const char* bufp = smem + ((t & 3) << 14);
    bf16x8 af[4], bg[4];
#pragma unroll
    for (int m = 0; m < 4; ++m)
      af[m] = *(const bf16x8*)(bufp + rdA + (m << 10));
#pragma unroll
    for (int n = 0; n < 4; ++n)
      bg[n] = *(const bf16x8*)(bufp + rdB + (n << 10));
    __builtin_amdgcn_s_setprio(1);
#pragma unroll
    for (int m = 0; m < 4; ++m)
#pragma unroll
      for (int n = 0; n < 4; ++n)
        acc[m][n] = __builtin_amdgcn_mfma_f32_16x16x32_bf16(af[m], bg[n],
                                                            acc[m][n], 0, 0, 0);
    __builtin_amdgcn_s_setprio(0);
    __builtin_amdgcn_sched_barrier(0);
    if (t + 3 < kT)       asm volatile("s_waitcnt vmcnt(8)" ::: "memory");
    else if (t + 3 == kT) asm volatile("s_waitcnt vmcnt(4)" ::: "memory");
    else if (t + 2 == kT) asm volatile("s_waitcnt vmcnt(0)" ::: "memory");
    if (t + 1 < kT) {
      __builtin_amdgcn_s_barrier();
      __builtin_amdgcn_sched_barrier(0);
      asm volatile("" ::: "memory");
    }
  }
#undef STGPV

  const int rl0 = (wr << 6) + (l4 << 2);
  const int cl0 = (wc << 6) + l15;
  __syncthreads();
#pragma unroll
  for (int m = 0; m < 4; ++m)
#pragma unroll
    for (int r = 0; r < 4; ++r) {
      const int ql = rl0 + m * 16 + r;
#pragma unroll
      for (int n = 0; n < 4; ++n) {
        const int colx = (cl0 + n * 16) ^ (l4 << 4);
        *(float*)(smem + ql * 512 + colx * 4) = acc[m][n][r];
      }
    }
  __syncthreads();
  const int* vb = vidx + (long)bz * SS;
#pragma unroll
  for (int i = 0; i < 16; ++i) {
    const int s2 = i * 256 + tid;
    const int row = s2 >> 5;
    const int cb = s2 & 31;
    const int lb = (row * 512 + (cb << 4)) ^ (((row >> 2) & 3) << 6);
    const int crow = bm * 128 + row;
    if (crow < nvb) {
      const int orig = vb[crow];
      *(uint4*)((char*)Out + (((long)bz * SS + orig) * HH) * 4 +
                (long)bn * 512 + (cb << 4)) = *(const uint4*)(smem + lb);
    }
  }
}

extern "C" void kernel_launch(void* const* d_in, const int* in_sizes, int n_in,
                              void* d_out, int out_size, void* d_ws, size_t ws_size,
                              hipStream_t stream) {
  (void)in_sizes; (void)n_in; (void)out_size; (void)ws_size;
  const float* x = (const float*)d_in[0];
  const unsigned char* mask_raw = (const unsigned char*)d_in[1];
  const float* Wq = (const float*)d_in[2];
  const float* bq = (const float*)d_in[3];
  const float* Wk = (const float*)d_in[4];
  const float* bk = (const float*)d_in[5];
  const float* Wv = (const float*)d_in[6];
  const float* bv = (const float*)d_in[7];
  char* ws = (char*)d_ws;

  unsigned short* Xbf = (unsigned short*)(ws + OFF_XBF);
  unsigned short* Wbf = (unsigned short*)(ws + OFF_WBF);
  unsigned short* Qc = (unsigned short*)(ws + OFF_Q);
  unsigned short* Kc = (unsigned short*)(ws + OFF_K);
  unsigned short* Vtc = (unsigned short*)(ws + OFF_VTC);
  unsigned char* mask = (unsigned char*)(ws + OFF_MASK);
  float* meanV = (float*)(ws + OFF_MEANV);
  int* vidx = (int*)(ws + OFF_VIDX);
  int* nv = (int*)(ws + OFF_NV);
  float* xsum = (float*)(ws + OFF_XSUM);
  int* qctl = (int*)(ws + OFF_QCTL);
  int* queue = (int*)(ws + OFF_QUEUE);

  const long MS = (long)BB * SS;  // 16384

  (void)hipFuncSetAttribute((const void*)gemm256q,
                            hipFuncAttributeMaxDynamicSharedMemorySize, 131088);

  // 0. zero queue ctl + xsum; canonicalize mask; build compaction + queue
  hipMemsetAsync(qctl, 0, 8, stream);
  hipMemsetAsync(xsum, 0, (size_t)BB * HH * 4, stream);
  canon_mask<<<1, 1024, 0, stream>>>(mask_raw, mask);
  build_compact<<<BB, 256, 0, stream>>>(mask, vidx, nv, qctl, queue);

  // 1. fp32 -> bf16
  cvt_f32_bf16<<<2048, 256, 0, stream>>>(x, Xbf, (int)(MS * HH / 4));
  cvt_w3<<<dim3(256, 3), 256, 0, stream>>>(Wq, Wk, Wv, Wbf);

  // 2. meanV via column sums of X (masked-row output needs only this)
  xsum_cols<<<dim3(32, BB), 256, 0, stream>>>(Xbf, xsum);
  meanv_dot<<<dim3(HH / 4, BB), 256, 0, stream>>>(
      xsum, Wbf + 2 * HH * HH, bv, meanV);

  // 3. fused QKV, work-queue (256 persistent blocks pop active tiles):
  //    all thirds M-compacted; z==2 writes compact Vtc directly
  gemm256q<<<256, 512, 131088, stream>>>(
      Xbf, Wbf, (long)HH * HH,
      (char*)Qc, (char*)Kc, (char*)Vtc, bq, bk, bv, vidx, queue, qctl);

  // 4. scores in compact space (pure triangular)
  gemm128s<<<dim3(NTRI, BB), 256, 0, stream>>>(
      Qc, Kc, ws + OFF_SCORES, nv);

  // 5. softmax over compact causal prefix (rows < nv only)
  softmax_tri<<<dim3(SS, BB), 256, 0, stream>>>(ws + OFF_SCORES, nv);

  // 6. PV in compact space; scatter rows to original positions
  gemm_pv<<<dim3(SS / 128, HH / 128, BB), 256, 0, stream>>>(
      ws + OFF_SCORES, Vtc, (float*)d_out, vidx, nv);

  // 7. masked query rows -> uniform mean of V
  fixup_masked<<<BB * SS, 256, 0, stream>>>((float*)d_out, mask, meanV);
}

// Round 17
// 239.099 us; speedup vs baseline: 1.1039x; 1.0289x over previous
//
#include <hip/hip_runtime.h>
#include <stdint.h>

typedef __bf16 bf16x8 __attribute__((ext_vector_type(8)));
typedef float f32x4 __attribute__((ext_vector_type(4)));

#define BB 8
#define SS 2048
#define HH 1024

// compact triangular scores: 128x128 tiles in COMPACTED key/query space.
#define TILE_B   32768ll
#define NTRI     136
#define BATCH_B  (NTRI * TILE_B)

// ws layout (bytes). Peak ~140 MiB.
#define OFF_Q      0ll
#define OFF_K      33554432ll
#define OFF_VTC    67108864ll
#define OFF_MASK   100663296ll
#define OFF_MEANV  100679680ll
#define OFF_VIDX   100712448ll
#define OFF_NV     100777984ll
#define OFF_XSUM   100778048ll   // fp32[8][1024]
#define OFF_QCTL   100843520ll   // int[8]: gemm{head,tail} sc{head,tail} pv{head,tail}
#define OFF_QUEUE  100843584ll   // int[768]  gemm
#define OFF_SQ     100846656ll   // int[1088] scores
#define OFF_PQ     100851008ll   // int[1024] pv
#define OFF_TMP    101711872ll
#define OFF_XBF    (OFF_TMP)
#define OFF_WBF    (OFF_TMP + 33554432ll)
#define OFF_SCORES (OFF_TMP + 39845888ll)

__device__ __forceinline__ unsigned short f2bf(float f) {
  unsigned int u = __float_as_uint(f);
  u += 0x7FFFu + ((u >> 16) & 1u);   // RTNE
  return (unsigned short)(u >> 16);
}
__device__ __forceinline__ float bf2f(unsigned short u) {
  return __uint_as_float(((unsigned int)u) << 16);
}

__device__ __forceinline__ void gl_lds16(const void* g, void* l) {
  __builtin_amdgcn_global_load_lds(
      (const __attribute__((address_space(1))) void*)g,
      (__attribute__((address_space(3))) void*)l, 16, 0, 0);
}

// ------- mask canonicalizer (uint8 / int32 / float32), 1024-thr vectorized --
__global__ __launch_bounds__(1024) void canon_mask(
    const unsigned char* __restrict__ m, unsigned char* __restrict__ out) {
  __shared__ int cnt[4];
  const int t = threadIdx.x;
  if (t < 4) cnt[t] = 0;
  __syncthreads();
  uint4 v = ((const uint4*)m)[t];
  const unsigned char* pb = (const unsigned char*)&v;
  int loc[4] = {0, 0, 0, 0};
#pragma unroll
  for (int j = 0; j < 16; ++j)
    if (pb[j]) loc[j & 3]++;
#pragma unroll
  for (int r = 0; r < 4; ++r)
    if (loc[r]) atomicAdd(&cnt[r], loc[r]);
  __syncthreads();
  const int c0 = cnt[0], c1 = cnt[1], c2 = cnt[2], c3 = cnt[3];
  unsigned char ob[16];
  if (c0 > 0 && c1 == 0 && c2 == 0 && c3 == 0) {        // int32 0/1
    const int* mi = (const int*)m;
#pragma unroll
    for (int j = 0; j < 16; ++j) ob[j] = mi[t * 16 + j] ? 1 : 0;
  } else if (c0 == 0 && (c2 > 0 || c3 > 0)) {           // float32
    const float* mf = (const float*)m;
#pragma unroll
    for (int j = 0; j < 16; ++j) ob[j] = (mf[t * 16 + j] != 0.0f) ? 1 : 0;
  } else {                                              // uint8 bool
#pragma unroll
    for (int j = 0; j < 16; ++j) ob[j] = pb[j] ? 1 : 0;
  }
  ((uint4*)out)[t] = *(const uint4*)ob;
}

// ------- per-batch compaction: vidx, nv, and all three work queues ----------
__global__ __launch_bounds__(256) void build_compact(
    const unsigned char* __restrict__ mask, int* __restrict__ vidx,
    int* __restrict__ nv, int* __restrict__ qctl, int* __restrict__ queue,
    int* __restrict__ sq, int* __restrict__ pq) {
  const int b = blockIdx.x;
  const int t = threadIdx.x;
  __shared__ int cnt[256];
  __shared__ int totalS;
  const unsigned char* mb = mask + b * SS;
  unsigned char m[8];
  int c = 0;
#pragma unroll
  for (int j = 0; j < 8; ++j) { m[j] = mb[t * 8 + j]; c += m[j] ? 1 : 0; }
  cnt[t] = c;
  __syncthreads();
  int base = 0;
  for (int i = 0; i < t; ++i) base += cnt[i];
  if (t == 255) totalS = base + c;
  int pos = base;
  int* vb = vidx + b * SS;
#pragma unroll
  for (int j = 0; j < 8; ++j) {
    const int s = t * 8 + j;
    if (m[j]) { vb[pos] = s; ++pos; }
  }
  __syncthreads();
  const int total = totalS;
  if (t == 0) {
    nv[b] = total;
    // gemm queue: (bm<<4)|(z<<2)|bn, 256-row tiles
    const int ntile = (total + 255) >> 8;
    {
      const int n = ntile * 12;
      const int qb = atomicAdd(&qctl[1], n);
      int k = 0;
      for (int tt = 0; tt < ntile; ++tt)
        for (int z = 0; z < 3; ++z)
          for (int bn = 0; bn < 4; ++bn)
            queue[qb + (k++)] = (((b << 3) | tt) << 4) | (z << 2) | bn;
    }
    // scores queue: (b<<8)|t0, triangular 128-tiles
    const int nt = (total + 127) >> 7;
    {
      const int ntri = nt * (nt + 1) / 2;
      const int qb = atomicAdd(&qctl[3], ntri);
      for (int t0 = 0; t0 < ntri; ++t0) sq[qb + t0] = (b << 8) | t0;
    }
    // pv queue: (b<<7)|(bm<<3)|bn, bm DESC (longest-first within batch)
    {
      const int n = nt * 8;
      const int qb = atomicAdd(&qctl[5], n);
      int k = 0;
      for (int bm = nt - 1; bm >= 0; --bm)
        for (int bn = 0; bn < 8; ++bn)
          pq[qb + (k++)] = (b << 7) | (bm << 3) | bn;
    }
  }
  for (int idx = total + t; idx < SS; idx += 256) vb[idx] = 0;
}

__global__ void cvt_f32_bf16(const float* __restrict__ in,
                             unsigned short* __restrict__ out, int n4) {
  int i = blockIdx.x * blockDim.x + threadIdx.x;
  int stride = gridDim.x * blockDim.x;
  for (; i < n4; i += stride) {
    float4 v = ((const float4*)in)[i];
    ushort4 o;
    o.x = f2bf(v.x); o.y = f2bf(v.y); o.z = f2bf(v.z); o.w = f2bf(v.w);
    ((ushort4*)out)[i] = o;
  }
}

__global__ void cvt_w3(const float* __restrict__ Wq, const float* __restrict__ Wk,
                       const float* __restrict__ Wv, unsigned short* __restrict__ out) {
  const int z = blockIdx.y;
  const float* src = (z == 0) ? Wq : (z == 1) ? Wk : Wv;
  unsigned short* dst = out + (long)z * (HH * HH);
  const int n4 = HH * HH / 4;
  int i = blockIdx.x * 256 + threadIdx.x;
  for (; i < n4; i += 256 * 256) {
    float4 v = ((const float4*)src)[i];
    ushort4 o;
    o.x = f2bf(v.x); o.y = f2bf(v.y); o.z = f2bf(v.z); o.w = f2bf(v.w);
    ((ushort4*)dst)[i] = o;
  }
}

// ------- per-batch column sums of Xbf (for meanV): xsum pre-zeroed ----------
__global__ __launch_bounds__(256) void xsum_cols(
    const unsigned short* __restrict__ Xbf, float* __restrict__ xsum) {
  const int b = blockIdx.y;
  const int sc = blockIdx.x;
  const int t = threadIdx.x;
  const unsigned short* base = Xbf + ((long)b * SS + sc * 64) * HH + t * 4;
  float s0 = 0.f, s1 = 0.f, s2 = 0.f, s3 = 0.f;
#pragma unroll 4
  for (int i = 0; i < 64; ++i) {
    ushort4 u = *(const ushort4*)(base + (long)i * HH);
    s0 += bf2f(u.x); s1 += bf2f(u.y); s2 += bf2f(u.z); s3 += bf2f(u.w);
  }
  float* xs = xsum + b * HH + t * 4;
  atomicAdd(&xs[0], s0); atomicAdd(&xs[1], s1);
  atomicAdd(&xs[2], s2); atomicAdd(&xs[3], s3);
}

// ------- meanV[b][h] = dot(xsum[b], Wv[h]) + 2048*bv[h] ---------------------
__global__ __launch_bounds__(256) void meanv_dot(
    const float* __restrict__ xsum, const unsigned short* __restrict__ Wvbf,
    const float* __restrict__ bv, float* __restrict__ meanV) {
  const int b = blockIdx.y;
  const int wave = threadIdx.x >> 6, lane = threadIdx.x & 63;
  const int h = blockIdx.x * 4 + wave;
  const unsigned short* wrow = Wvbf + (long)h * HH + lane * 16;
  const float* xs = xsum + b * HH + lane * 16;
  float s = 0.f;
#pragma unroll
  for (int j = 0; j < 4; ++j) {
    ushort4 u = *(const ushort4*)(wrow + j * 4);
    s += bf2f(u.x) * xs[j * 4 + 0] + bf2f(u.y) * xs[j * 4 + 1] +
         bf2f(u.z) * xs[j * 4 + 2] + bf2f(u.w) * xs[j * 4 + 3];
  }
#pragma unroll
  for (int off = 32; off > 0; off >>= 1) s += __shfl_down(s, off, 64);
  if (lane == 0) meanV[(long)b * HH + h] = s + 2048.0f * bv[h];
}

// masked query rows -> uniform mean of V
__global__ __launch_bounds__(256) void fixup_masked(
    float* __restrict__ out, const unsigned char* __restrict__ mask,
    const float* __restrict__ sums) {
  const long row = blockIdx.x;
  if (mask[row]) return;
  const long b = row >> 11;
  const int t = threadIdx.x;
  float4 v = ((const float4*)(sums + b * HH))[t];
  v.x *= (1.f / 2048.f); v.y *= (1.f / 2048.f);
  v.z *= (1.f / 2048.f); v.w *= (1.f / 2048.f);
  ((float4*)(out + row * HH))[t] = v;
}

// ===== 256x256 fused QKV — WORK-QUEUE 8-phase core, all-M-compact (r16) =====
__global__ __launch_bounds__(512, 2) void gemm256q(
    const unsigned short* __restrict__ Abase,
    const unsigned short* __restrict__ Bbase, long bStride,
    char* __restrict__ Cq, char* __restrict__ Ck, char* __restrict__ VtcOut,
    const float* __restrict__ biasq, const float* __restrict__ biask,
    const float* __restrict__ biasv,
    const int* __restrict__ vidx, const int* __restrict__ queue,
    int* __restrict__ qctl) {
  extern __shared__ char smem[];
  int* bc = (int*)(smem + 131072);
  const int tid = threadIdx.x;
  const int wave = tid >> 6, lane = tid & 63;
  const int wr = wave >> 2, wc = wave & 3;
  const int l15 = lane & 15, l4 = lane >> 4;

  const int srow = tid >> 3;
  const int gslot = (tid & 7) ^ (srow & 7);
  const int ldsStageW = wave << 10;
  const int sw0 = ((l4 ^ (l15 & 7)) << 4);
  const int sw1 = (((4 + l4) ^ (l15 & 7)) << 4);
  const int aB0 = (wr << 14) + l15 * 128 + sw0;
  const int aB1 = (wr << 14) + l15 * 128 + sw1;
  const int bB0 = 32768 + ((wc >> 1) << 14) + (((wc & 1) << 6) + l15) * 128 + sw0;
  const int bB1 = 32768 + ((wc >> 1) << 14) + (((wc & 1) << 6) + l15) * 128 + sw1;
  const int rl0 = (wr << 7) + (l4 << 2);
  const int cl0 = (wc << 6) + l15;
  const int qcnt = qctl[1];

  for (;;) {
    __syncthreads();
    if (tid == 0) *bc = atomicAdd(&qctl[0], 1);
    __syncthreads();
    const int idx = *bc;
    if (idx >= qcnt) break;
    const int e = queue[idx];
    const int bm = e >> 4;
    const int bz = (e >> 2) & 3;
    const int bn = e & 3;
    const int b = bm >> 3;
    const int rInB = (bm & 7) * 256;

    const int* vb = vidx + b * SS;
    const char* aS[4];
#pragma unroll
    for (int j = 0; j < 4; ++j) {
      const int r = rInB + srow + 64 * j;
      aS[j] = (const char*)Abase + ((long)b * SS + vb[r]) * 2048 + gslot * 16;
    }
    const char* gB = (const char*)(Bbase + (long)bz * bStride) +
                     ((long)bn * 256 + srow) * 2048 + gslot * 16;

#define STG(kt_, type_, buf_) do { \
    char* _l = smem + ((buf_) << 16) + (((type_) >> 1) << 15) + \
               (((type_) & 1) << 14) + ldsStageW; \
    if ((type_) < 2) { \
      gl_lds16(aS[(type_) * 2]     + ((long)(kt_) << 7), _l); \
      gl_lds16(aS[(type_) * 2 + 1] + ((long)(kt_) << 7), _l + 8192); \
    } else { \
      const char* _g = gB + (((type_) & 1) ? 262144 : 0) + ((long)(kt_) << 7); \
      gl_lds16(_g, _l); \
      gl_lds16(_g + 131072, _l + 8192); \
    } } while (0)

    f32x4 acc[8][4];
    const f32x4 z4 = {0.f, 0.f, 0.f, 0.f};
#pragma unroll
    for (int m = 0; m < 8; ++m)
#pragma unroll
      for (int n = 0; n < 4; ++n) acc[m][n] = z4;

    STG(0, 0, 0); STG(0, 1, 0); STG(0, 2, 0); STG(0, 3, 0);
    STG(1, 0, 1); STG(1, 1, 1); STG(1, 2, 1); STG(1, 3, 1);
    asm volatile("s_waitcnt vmcnt(8)" ::: "memory");
    __builtin_amdgcn_s_barrier();
    __builtin_amdgcn_sched_barrier(0);

    bf16x8 aC[4][2], bLo[2][2], bHi[2][2];

    for (int it = 0; it < 8; ++it) {
#pragma unroll
      for (int g = 0; g < 8; ++g) {
        const int buf = (g < 4) ? 0 : 65536;
        const int q = g & 3;
        if (q == 0) {
#pragma unroll
          for (int mm = 0; mm < 4; ++mm) {
            aC[mm][0] = *(const bf16x8*)(smem + buf + aB0 + mm * 2048);
            aC[mm][1] = *(const bf16x8*)(smem + buf + aB1 + mm * 2048);
          }
#pragma unroll
          for (int nn = 0; nn < 2; ++nn) {
            bLo[nn][0] = *(const bf16x8*)(smem + buf + bB0 + nn * 2048);
            bLo[nn][1] = *(const bf16x8*)(smem + buf + bB1 + nn * 2048);
          }
        } else if (q == 1) {
#pragma unroll
          for (int nn = 0; nn < 2; ++nn) {
            bHi[nn][0] = *(const bf16x8*)(smem + buf + bB0 + (2 + nn) * 2048);
            bHi[nn][1] = *(const bf16x8*)(smem + buf + bB1 + (2 + nn) * 2048);
          }
        } else if (q == 2) {
#pragma unroll
          for (int mm = 0; mm < 4; ++mm) {
            aC[mm][0] = *(const bf16x8*)(smem + buf + aB0 + (4 + mm) * 2048);
            aC[mm][1] = *(const bf16x8*)(smem + buf + aB1 + (4 + mm) * 2048);
          }
        }
        {
          const int u = it * 8 + g - 2;
          if (u >= 0) {
            const int kt = 2 + (u >> 2);
            if (kt < 16) {
              if (g == 0)      STG(kt, 0, 1);
              else if (g == 1) STG(kt, 1, 1);
              else if (g == 2) STG(kt, 2, 0);
              else if (g == 3) STG(kt, 3, 0);
              else if (g == 4) STG(kt, 0, 0);
              else if (g == 5) STG(kt, 1, 0);
              else if (g == 6) STG(kt, 2, 1);
              else             STG(kt, 3, 1);
            }
          }
        }
        __builtin_amdgcn_s_barrier();
        asm volatile("s_waitcnt lgkmcnt(0)" ::: "memory");
        __builtin_amdgcn_sched_barrier(0);
        __builtin_amdgcn_s_setprio(1);
        if (q == 0) {
#pragma unroll
          for (int mm = 0; mm < 4; ++mm)
#pragma unroll
            for (int nn = 0; nn < 2; ++nn) {
              acc[mm][nn] = __builtin_amdgcn_mfma_f32_16x16x32_bf16(
                  aC[mm][0], bLo[nn][0], acc[mm][nn], 0, 0, 0);
              acc[mm][nn] = __builtin_amdgcn_mfma_f32_16x16x32_bf16(
                  aC[mm][1], bLo[nn][1], acc[mm][nn], 0, 0, 0);
            }
        } else if (q == 1) {
#pragma unroll
          for (int mm = 0; mm < 4; ++mm)
#pragma unroll
            for (int nn = 0; nn < 2; ++nn) {
              acc[mm][2 + nn] = __builtin_amdgcn_mfma_f32_16x16x32_bf16(
                  aC[mm][0], bHi[nn][0], acc[mm][2 + nn], 0, 0, 0);
              acc[mm][2 + nn] = __builtin_amdgcn_mfma_f32_16x16x32_bf16(
                  aC[mm][1], bHi[nn][1], acc[mm][2 + nn], 0, 0, 0);
            }
        } else if (q == 2) {
#pragma unroll
          for (int mm = 0; mm < 4; ++mm)
#pragma unroll
            for (int nn = 0; nn < 2; ++nn) {
              acc[4 + mm][2 + nn] = __builtin_amdgcn_mfma_f32_16x16x32_bf16(
                  aC[mm][0], bHi[nn][0], acc[4 + mm][2 + nn], 0, 0, 0);
              acc[4 + mm][2 + nn] = __builtin_amdgcn_mfma_f32_16x16x32_bf16(
                  aC[mm][1], bHi[nn][1], acc[4 + mm][2 + nn], 0, 0, 0);
            }
        } else {
#pragma unroll
          for (int mm = 0; mm < 4; ++mm)
#pragma unroll
            for (int nn = 0; nn < 2; ++nn) {
              acc[4 + mm][nn] = __builtin_amdgcn_mfma_f32_16x16x32_bf16(
                  aC[mm][0], bLo[nn][0], acc[4 + mm][nn], 0, 0, 0);
              acc[4 + mm][nn] = __builtin_amdgcn_mfma_f32_16x16x32_bf16(
                  aC[mm][1], bLo[nn][1], acc[4 + mm][nn], 0, 0, 0);
            }
        }
        __builtin_amdgcn_s_setprio(0);
        __builtin_amdgcn_sched_barrier(0);
        if (q == 3) {
          if (g == 3 && it == 7)
            asm volatile("s_waitcnt vmcnt(0)" ::: "memory");
          else
            asm volatile("s_waitcnt vmcnt(4)" ::: "memory");
        }
        __builtin_amdgcn_s_barrier();
        asm volatile("" ::: "memory");
      }
    }
#undef STG

    if (bz < 2) {
      const float* bias = (bz == 0) ? biasq : biask;
#pragma unroll
      for (int n = 0; n < 4; ++n) {
        const int cl = cl0 + n * 16;
        const float bv = bias[bn * 256 + cl];
        const int colx = cl ^ (l4 << 4);
#pragma unroll
        for (int m = 0; m < 8; ++m) {
          const int rl = rl0 + m * 16;
#pragma unroll
          for (int r = 0; r < 4; ++r)
            *(unsigned short*)(smem + (rl + r) * 512 + colx * 2) =
                f2bf(acc[m][n][r] + bv);
        }
      }
      __syncthreads();
      unsigned short* C = (unsigned short*)((bz == 0) ? Cq : Ck);
      const long rowg0 = (long)b * SS + rInB;
      const long colb0 = (long)bn * 512;
#pragma unroll
      for (int i = 0; i < 16; ++i) {
        const int s2 = i * 512 + tid;
        const int row = s2 >> 5;
        const int cb = s2 & 31;
        const int lb = (row * 512 + (cb << 4)) ^ (((row >> 2) & 3) << 5);
        *(uint4*)((char*)C + (rowg0 + row) * 2048 + colb0 + (cb << 4)) =
            *(const uint4*)(smem + lb);
      }
    } else {
#pragma unroll
      for (int n = 0; n < 4; ++n) {
        const int h = cl0 + n * 16;
        const float bv = biasv[bn * 256 + h];
        const int xr = (h & 7) << 4;
#pragma unroll
        for (int m = 0; m < 8; ++m) {
          const int s0a = rl0 + m * 16;
          uint2 w;
          w.x = (unsigned)f2bf(acc[m][n][0] + bv) |
                ((unsigned)f2bf(acc[m][n][1] + bv) << 16);
          w.y = (unsigned)f2bf(acc[m][n][2] + bv) |
                ((unsigned)f2bf(acc[m][n][3] + bv) << 16);
          *(uint2*)(smem + h * 512 + ((s0a * 2) ^ xr)) = w;
        }
      }
      __syncthreads();
      char* VtB = VtcOut + (long)b * (SS * HH * 2) + (long)(bm & 7) * 512;
#pragma unroll
      for (int i = 0; i < 16; ++i) {
        const int s2 = i * 512 + tid;
        const int h = s2 >> 5;
        const int cb = s2 & 31;
        const int lb = h * 512 + ((cb << 4) ^ ((h & 7) << 4));
        *(uint4*)(VtB + (long)(bn * 256 + h) * 4096 + cb * 16) =
            *(const uint4*)(smem + lb);
      }
    }
  }
}

// -------- WORK-QUEUE 128x128 core: SCORES (compact, pure triangular) --------
__global__ __launch_bounds__(256, 2) void gemm128s(
    const unsigned short* __restrict__ Qc, const unsigned short* __restrict__ Kc,
    char* __restrict__ scoresBase, const int* __restrict__ sq,
    int* __restrict__ qctl) {
  __shared__ __align__(16) char smem[65536];
  __shared__ int bc;
  const int tid = threadIdx.x;
  const int wave = tid >> 6, lane = tid & 63;
  const int wr = wave >> 1, wc = wave & 1;
  const int l15 = lane & 15, l4 = lane >> 4;

  const int s0 = tid, s1 = tid + 256;
  const int rA0 = ((s0 >> 3) << 1) | (((s0 >> 2) & 1) ^ ((s0 >> 4) & 1));
  const int cA0 = (s0 & 3) ^ (rA0 & 3);
  const int rA1 = ((s1 >> 3) << 1) | (((s1 >> 2) & 1) ^ ((s1 >> 4) & 1));
  const int cA1 = (s1 & 3) ^ (rA1 & 3);
  const int ldsL0 = wave << 10;
  const int ldsL1 = 4096 + (wave << 10);
  const int baseSwz = ((l15 * 64 + (l4 << 4)) ^ ((l15 & 7) << 4));
  const int rdA = (wr << 12) + baseSwz;
  const int rdB = 8192 + (wc << 12) + baseSwz;
  const int rl0 = (wr << 6) + (l4 << 2);
  const int cl0 = (wc << 6) + l15;
  const int qcnt = qctl[3];

  for (;;) {
    __syncthreads();
    if (tid == 0) bc = atomicAdd(&qctl[2], 1);
    __syncthreads();
    const int idx = bc;
    if (idx >= qcnt) break;
    const int e = sq[idx];
    const int bz = e >> 8;
    int t0 = e & 255, bm = 0, a_ = 0;
    while (a_ + bm + 1 <= t0) { ++bm; a_ += bm; }
    const int bn = t0 - a_;

    const unsigned short* A = Qc + (long)bz * SS * HH;
    const unsigned short* B = Kc + (long)bz * SS * HH;
    const char* aG0 = (const char*)A + (long)(bm * 128 + rA0) * 2048 + cA0 * 16;
    const char* aG1 = (const char*)A + (long)(bm * 128 + rA1) * 2048 + cA1 * 16;
    const char* bG0 = (const char*)B + (long)(bn * 128 + rA0) * 2048 + cA0 * 16;
    const char* bG1 = (const char*)B + (long)(bn * 128 + rA1) * 2048 + cA1 * 16;

#define STG(t_) do { \
    char* _p = smem + (((t_) & 3) << 14); \
    const long _ko = (long)(t_) << 6; \
    gl_lds16(aG0 + _ko, _p + ldsL0); \
    gl_lds16(aG1 + _ko, _p + ldsL1); \
    gl_lds16(bG0 + _ko, _p + 8192 + ldsL0); \
    gl_lds16(bG1 + _ko, _p + 8192 + ldsL1); } while (0)

    f32x4 acc[4][4];
    const f32x4 z4 = {0.f, 0.f, 0.f, 0.f};
#pragma unroll
    for (int m = 0; m < 4; ++m)
#pragma unroll
      for (int n = 0; n < 4; ++n) acc[m][n] = z4;

    STG(0); STG(1); STG(2);
    asm volatile("s_waitcnt vmcnt(8)" ::: "memory");
    __builtin_amdgcn_s_barrier();
    __builtin_amdgcn_sched_barrier(0);

    const int kT = 32;
    for (int t = 0; t < kT; ++t) {
      if (t + 3 < kT) STG(t + 3);
      const char* bufp = smem + ((t & 3) << 14);
      bf16x8 af[4], bg[4];
#pragma unroll
      for (int m = 0; m < 4; ++m)
        af[m] = *(const bf16x8*)(bufp + rdA + (m << 10));
#pragma unroll
      for (int n = 0; n < 4; ++n)
        bg[n] = *(const bf16x8*)(bufp + rdB + (n << 10));
      __builtin_amdgcn_s_setprio(1);
#pragma unroll
      for (int m = 0; m < 4; ++m)
#pragma unroll
        for (int n = 0; n < 4; ++n)
          acc[m][n] = __builtin_amdgcn_mfma_f32_16x16x32_bf16(af[m], bg[n],
                                                              acc[m][n], 0, 0, 0);
      __builtin_amdgcn_s_setprio(0);
      __builtin_amdgcn_sched_barrier(0);
      if (t + 3 < kT)       asm volatile("s_waitcnt vmcnt(8)" ::: "memory");
      else if (t + 3 == kT) asm volatile("s_waitcnt vmcnt(4)" ::: "memory");
      else if (t + 2 == kT) asm volatile("s_waitcnt vmcnt(0)" ::: "memory");
      if (t + 1 < kT) {
        __builtin_amdgcn_s_barrier();
        __builtin_amdgcn_sched_barrier(0);
        asm volatile("" ::: "memory");
      }
    }
#undef STG

    char* Ct = scoresBase + (long)bz * BATCH_B + (long)t0 * TILE_B;
    __syncthreads();
#pragma unroll
    for (int m = 0; m < 4; ++m)
#pragma unroll
      for (int r = 0; r < 4; ++r) {
        const int ql = rl0 + m * 16 + r;
        const int qg = bm * 128 + ql;
#pragma unroll
        for (int n = 0; n < 4; ++n) {
          const int kg = bn * 128 + cl0 + n * 16;
          const float v = (kg <= qg) ? acc[m][n][r] * 0.03125f : -1.0e9f;
          const int colx = (cl0 + n * 16) ^ (l4 << 4);
          *(unsigned short*)(smem + ql * 256 + colx * 2) = f2bf(v);
        }
      }
    __syncthreads();
#pragma unroll
    for (int i = 0; i < 8; ++i) {
      const int s2 = i * 256 + tid;
      const int row = s2 >> 4;
      const int cb = s2 & 15;
      const int lb = row * 256 + ((cb << 4) ^ (((row >> 2) & 3) << 5));
      *(uint4*)(Ct + (long)row * 256 + (cb << 4)) = *(const uint4*)(smem + lb);
    }
  }
}

// ------------- softmax over compact causal prefix, bf16 128-tiles -----------
__global__ __launch_bounds__(256) void softmax_tri(char* __restrict__ base,
                                                   const int* __restrict__ nv) {
  const int r = blockIdx.x;
  const int bz = blockIdx.y;
  if (r >= nv[bz]) return;
  const int bm = r >> 7;
  const int w = (bm + 1) << 7;
  char* bb = base + (long)bz * BATCH_B +
             (long)(bm * (bm + 1) / 2) * TILE_B + (long)(r & 127) * 256;
  const int t = threadIdx.x;
  const bool act = (t << 3) < w;
  const int bn = t >> 4;
  const int cl = (t << 3) & 127;
  char* slot = bb + (long)bn * TILE_B + (long)cl * 2;
  float v[8];
  float m = -3.0e38f;
  if (act) {
    ushort4 u0 = ((const ushort4*)slot)[0];
    ushort4 u1 = ((const ushort4*)slot)[1];
    v[0] = bf2f(u0.x); v[1] = bf2f(u0.y); v[2] = bf2f(u0.z); v[3] = bf2f(u0.w);
    v[4] = bf2f(u1.x); v[5] = bf2f(u1.y); v[6] = bf2f(u1.z); v[7] = bf2f(u1.w);
#pragma unroll
    for (int k = 0; k < 8; ++k) m = fmaxf(m, v[k]);
  }
  __shared__ float red[8];
#pragma unroll
  for (int off = 32; off > 0; off >>= 1) m = fmaxf(m, __shfl_down(m, off, 64));
  const int wid = t >> 6, lane = t & 63;
  if (lane == 0) red[wid] = m;
  __syncthreads();
  m = fmaxf(fmaxf(red[0], red[1]), fmaxf(red[2], red[3]));
  float e[8];
  float s = 0.f;
  if (act) {
#pragma unroll
    for (int k = 0; k < 8; ++k) { e[k] = __expf(v[k] - m); s += e[k]; }
  }
#pragma unroll
  for (int off = 32; off > 0; off >>= 1) s += __shfl_down(s, off, 64);
  if (lane == 0) red[4 + wid] = s;
  __syncthreads();
  s = red[4] + red[5] + red[6] + red[7];
  const float inv = 1.0f / s;
  if (act) {
    ushort4 o0, o1;
    o0.x = f2bf(e[0] * inv); o0.y = f2bf(e[1] * inv);
    o0.z = f2bf(e[2] * inv); o0.w = f2bf(e[3] * inv);
    o1.x = f2bf(e[4] * inv); o1.y = f2bf(e[5] * inv);
    o1.z = f2bf(e[6] * inv); o1.w = f2bf(e[7] * inv);
    ((ushort4*)slot)[0] = o0;
    ((ushort4*)slot)[1] = o1;
  }
}

// -------- WORK-QUEUE 128x128 core: PV (compact, scatter output) -------------
__global__ __launch_bounds__(256, 2) void gemm_pv(
    const char* __restrict__ attn, const unsigned short* __restrict__ Vtc,
    float* __restrict__ Out, const int* __restrict__ vidx,
    const int* __restrict__ nv, const int* __restrict__ pq,
    int* __restrict__ qctl) {
  __shared__ __align__(16) char smem[65536];
  __shared__ int bc;
  const int tid = threadIdx.x;
  const int wave = tid >> 6, lane = tid & 63;
  const int wr = wave >> 1, wc = wave & 1;
  const int l15 = lane & 15, l4 = lane >> 4;

  const int s0 = tid, s1 = tid + 256;
  const int rA0 = ((s0 >> 3) << 1) | (((s0 >> 2) & 1) ^ ((s0 >> 4) & 1));
  const int cA0 = (s0 & 3) ^ (rA0 & 3);
  const int rA1 = ((s1 >> 3) << 1) | (((s1 >> 2) & 1) ^ ((s1 >> 4) & 1));
  const int cA1 = (s1 & 3) ^ (rA1 & 3);
  const int ldsL0 = wave << 10;
  const int ldsL1 = 4096 + (wave << 10);
  const int baseSwz = ((l15 * 64 + (l4 << 4)) ^ ((l15 & 7) << 4));
  const int rdA = (wr << 12) + baseSwz;
  const int rdB = 8192 + (wc << 12) + baseSwz;
  const int rl0 = (wr << 6) + (l4 << 2);
  const int cl0 = (wc << 6) + l15;
  const int qcnt = qctl[5];

  for (;;) {
    __syncthreads();
    if (tid == 0) bc = atomicAdd(&qctl[4], 1);
    __syncthreads();
    const int idx = bc;
    if (idx >= qcnt) break;
    const int e = pq[idx];
    const int bz = e >> 7;
    const int bm = (e >> 3) & 15;
    const int bn = e & 7;
    const int nvb = nv[bz];

    const char* Ab = attn + (long)bz * BATCH_B +
                     (long)(bm * (bm + 1) / 2) * TILE_B;
    const unsigned short* B = Vtc + (long)bz * SS * HH;
    const char* aB0 = Ab + (long)rA0 * 256 + cA0 * 16;
    const char* aB1 = Ab + (long)rA1 * 256 + cA1 * 16;
    const char* bG0 = (const char*)(B + (long)(bn * 128 + rA0) * SS) + cA0 * 16;
    const char* bG1 = (const char*)(B + (long)(bn * 128 + rA1) * SS) + cA1 * 16;

#define STGPV(t_) do { \
    char* _p = smem + (((t_) & 3) << 14); \
    const long _aO = (long)((t_) >> 2) * TILE_B + (long)((t_) & 3) * 64; \
    const long _bO = (long)(t_) << 6; \
    gl_lds16(aB0 + _aO, _p + ldsL0); \
    gl_lds16(aB1 + _aO, _p + ldsL1); \
    gl_lds16(bG0 + _bO, _p + 8192 + ldsL0); \
    gl_lds16(bG1 + _bO, _p + 8192 + ldsL1); } while (0)

    f32x4 acc[4][4];
    const f32x4 z4 = {0.f, 0.f, 0.f, 0.f};
#pragma unroll
    for (int m = 0; m < 4; ++m)
#pragma unroll
      for (int n = 0; n < 4; ++n) acc[m][n] = z4;

    STGPV(0); STGPV(1); STGPV(2);
    asm volatile("s_waitcnt vmcnt(8)" ::: "memory");
    __builtin_amdgcn_s_barrier();
    __builtin_amdgcn_sched_barrier(0);

    const int kT = (bm + 1) * 4;
    for (int t = 0; t < kT; ++t) {
      if (t + 3 < kT) STGPV(t + 3);
      const char* bufp = smem + ((t & 3) << 14);
      bf16x8 af[4], bg[4];
#pragma unroll
      for (int m = 0; m < 4; ++m)
        af[m] = *(const bf16x8*)(bufp + rdA + (m << 10));
#pragma unroll
      for (int n = 0; n < 4; ++n)
        bg[n] = *(const bf16x8*)(bufp + rdB + (n << 10));
      __builtin_amdgcn_s_setprio(1);
#pragma unroll
      for (int m = 0; m < 4; ++m)
#pragma unroll
        for (int n = 0; n < 4; ++n)
          acc[m][n] = __builtin_amdgcn_mfma_f32_16x16x32_bf16(af[m], bg[n],
                                                              acc[m][n], 0, 0, 0);
      __builtin_amdgcn_s_setprio(0);
      __builtin_amdgcn_sched_barrier(0);
      if (t + 3 < kT)       asm volatile("s_waitcnt vmcnt(8)" ::: "memory");
      else if (t + 3 == kT) asm volatile("s_waitcnt vmcnt(4)" ::: "memory");
      else if (t + 2 == kT) asm volatile("s_waitcnt vmcnt(0)" ::: "memory");
      if (t + 1 < kT) {
        __builtin_amdgcn_s_barrier();
        __builtin_amdgcn_sched_barrier(0);
        asm volatile("" ::: "memory");
      }
    }
#undef STGPV

    __syncthreads();
#pragma unroll
    for (int m = 0; m < 4; ++m)
#pragma unroll
      for (int r = 0; r < 4; ++r) {
        const int ql = rl0 + m * 16 + r;
#pragma unroll
        for (int n = 0; n < 4; ++n) {
          const int colx = (cl0 + n * 16) ^ (l4 << 4);
          *(float*)(smem + ql * 512 + colx * 4) = acc[m][n][r];
        }
      }
    __syncthreads();
    const int* vb = vidx + (long)bz * SS;
#pragma unroll
    for (int i = 0; i < 16; ++i) {
      const int s2 = i * 256 + tid;
      const int row = s2 >> 5;
      const int cb = s2 & 31;
      const int lb = (row * 512 + (cb << 4)) ^ (((row >> 2) & 3) << 6);
      const int crow = bm * 128 + row;
      if (crow < nvb) {
        const int orig = vb[crow];
        *(uint4*)((char*)Out + (((long)bz * SS + orig) * HH) * 4 +
                  (long)bn * 512 + (cb << 4)) = *(const uint4*)(smem + lb);
      }
    }
  }
}

extern "C" void kernel_launch(void* const* d_in, const int* in_sizes, int n_in,
                              void* d_out, int out_size, void* d_ws, size_t ws_size,
                              hipStream_t stream) {
  (void)in_sizes; (void)n_in; (void)out_size; (void)ws_size;
  const float* x = (const float*)d_in[0];
  const unsigned char* mask_raw = (const unsigned char*)d_in[1];
  const float* Wq = (const float*)d_in[2];
  const float* bq = (const float*)d_in[3];
  const float* Wk = (const float*)d_in[4];
  const float* bk = (const float*)d_in[5];
  const float* Wv = (const float*)d_in[6];
  const float* bv = (const float*)d_in[7];
  char* ws = (char*)d_ws;

  unsigned short* Xbf = (unsigned short*)(ws + OFF_XBF);
  unsigned short* Wbf = (unsigned short*)(ws + OFF_WBF);
  unsigned short* Qc = (unsigned short*)(ws + OFF_Q);
  unsigned short* Kc = (unsigned short*)(ws + OFF_K);
  unsigned short* Vtc = (unsigned short*)(ws + OFF_VTC);
  unsigned char* mask = (unsigned char*)(ws + OFF_MASK);
  float* meanV = (float*)(ws + OFF_MEANV);
  int* vidx = (int*)(ws + OFF_VIDX);
  int* nv = (int*)(ws + OFF_NV);
  float* xsum = (float*)(ws + OFF_XSUM);
  int* qctl = (int*)(ws + OFF_QCTL);
  int* queue = (int*)(ws + OFF_QUEUE);
  int* sq = (int*)(ws + OFF_SQ);
  int* pq = (int*)(ws + OFF_PQ);

  const long MS = (long)BB * SS;  // 16384

  (void)hipFuncSetAttribute((const void*)gemm256q,
                            hipFuncAttributeMaxDynamicSharedMemorySize, 131088);

  // 0. zero queue ctl + xsum; canonicalize mask; build compaction + queues
  hipMemsetAsync(qctl, 0, 32, stream);
  hipMemsetAsync(xsum, 0, (size_t)BB * HH * 4, stream);
  canon_mask<<<1, 1024, 0, stream>>>(mask_raw, mask);
  build_compact<<<BB, 256, 0, stream>>>(mask, vidx, nv, qctl, queue, sq, pq);

  // 1. fp32 -> bf16
  cvt_f32_bf16<<<2048, 256, 0, stream>>>(x, Xbf, (int)(MS * HH / 4));
  cvt_w3<<<dim3(256, 3), 256, 0, stream>>>(Wq, Wk, Wv, Wbf);

  // 2. meanV via column sums of X
  xsum_cols<<<dim3(32, BB), 256, 0, stream>>>(Xbf, xsum);
  meanv_dot<<<dim3(HH / 4, BB), 256, 0, stream>>>(
      xsum, Wbf + 2 * HH * HH, bv, meanV);

  // 3. fused QKV, work-queue (256 persistent blocks)
  gemm256q<<<256, 512, 131088, stream>>>(
      Xbf, Wbf, (long)HH * HH,
      (char*)Qc, (char*)Kc, (char*)Vtc, bq, bk, bv, vidx, queue, qctl);

  // 4. scores, work-queue (512 persistent blocks, 2/CU)
  gemm128s<<<512, 256, 0, stream>>>(Qc, Kc, ws + OFF_SCORES, sq, qctl);

  // 5. softmax over compact causal prefix
  softmax_tri<<<dim3(SS, BB), 256, 0, stream>>>(ws + OFF_SCORES, nv);

  // 6. PV, work-queue (512 persistent blocks, longest-first entries)
  gemm_pv<<<512, 256, 0, stream>>>(
      ws + OFF_SCORES, Vtc, (float*)d_out, vidx, nv, pq, qctl);

  // 7. masked query rows -> uniform mean of V
  fixup_masked<<<BB * SS, 256, 0, stream>>>((float*)d_out, mask, meanV);
}

// Round 18
// 236.087 us; speedup vs baseline: 1.1180x; 1.0128x over previous
//
#include <hip/hip_runtime.h>
#include <stdint.h>

typedef __bf16 bf16x8 __attribute__((ext_vector_type(8)));
typedef float f32x4 __attribute__((ext_vector_type(4)));

#define BB 8
#define SS 2048
#define HH 1024

// compact triangular scores: 128x128 tiles in COMPACTED key/query space.
#define TILE_B   32768ll
#define NTRI     136
#define BATCH_B  (NTRI * TILE_B)

// ws layout (bytes). Peak ~140 MiB.
#define OFF_Q      0ll
#define OFF_K      33554432ll
#define OFF_VTC    67108864ll
#define OFF_MASK   100663296ll
#define OFF_MEANV  100679680ll
#define OFF_VIDX   100712448ll
#define OFF_NV     100777984ll
#define OFF_XSUM   100778048ll   // fp32[8][1024]
#define OFF_QCTL   100843520ll   // int[8]
#define OFF_QUEUE  100843584ll   // int[768]  gemm
#define OFF_SQ     100846656ll   // int[1088] scores
#define OFF_PQ     100851008ll   // int[1024] pv
#define OFF_TMP    101711872ll
#define OFF_XC     (OFF_TMP)                 // compact X bf16 (32M)
#define OFF_WBF    (OFF_TMP + 33554432ll)
#define OFF_SCORES (OFF_TMP + 39845888ll)

__device__ __forceinline__ unsigned short f2bf(float f) {
  unsigned int u = __float_as_uint(f);
  u += 0x7FFFu + ((u >> 16) & 1u);   // RTNE
  return (unsigned short)(u >> 16);
}
__device__ __forceinline__ float bf2f(unsigned short u) {
  return __uint_as_float(((unsigned int)u) << 16);
}

__device__ __forceinline__ void gl_lds16(const void* g, void* l) {
  __builtin_amdgcn_global_load_lds(
      (const __attribute__((address_space(1))) void*)g,
      (__attribute__((address_space(3))) void*)l, 16, 0, 0);
}

// ------- mask canonicalizer (uint8 / int32 / float32), 1024-thr vectorized --
__global__ __launch_bounds__(1024) void canon_mask(
    const unsigned char* __restrict__ m, unsigned char* __restrict__ out) {
  __shared__ int cnt[4];
  const int t = threadIdx.x;
  if (t < 4) cnt[t] = 0;
  __syncthreads();
  uint4 v = ((const uint4*)m)[t];
  const unsigned char* pb = (const unsigned char*)&v;
  int loc[4] = {0, 0, 0, 0};
#pragma unroll
  for (int j = 0; j < 16; ++j)
    if (pb[j]) loc[j & 3]++;
#pragma unroll
  for (int r = 0; r < 4; ++r)
    if (loc[r]) atomicAdd(&cnt[r], loc[r]);
  __syncthreads();
  const int c0 = cnt[0], c1 = cnt[1], c2 = cnt[2], c3 = cnt[3];
  unsigned char ob[16];
  if (c0 > 0 && c1 == 0 && c2 == 0 && c3 == 0) {        // int32 0/1
    const int* mi = (const int*)m;
#pragma unroll
    for (int j = 0; j < 16; ++j) ob[j] = mi[t * 16 + j] ? 1 : 0;
  } else if (c0 == 0 && (c2 > 0 || c3 > 0)) {           // float32
    const float* mf = (const float*)m;
#pragma unroll
    for (int j = 0; j < 16; ++j) ob[j] = (mf[t * 16 + j] != 0.0f) ? 1 : 0;
  } else {                                              // uint8 bool
#pragma unroll
    for (int j = 0; j < 16; ++j) ob[j] = pb[j] ? 1 : 0;
  }
  ((uint4*)out)[t] = *(const uint4*)ob;
}

// ------- per-batch compaction: vidx, nv, and all three work queues ----------
__global__ __launch_bounds__(256) void build_compact(
    const unsigned char* __restrict__ mask, int* __restrict__ vidx,
    int* __restrict__ nv, int* __restrict__ qctl, int* __restrict__ queue,
    int* __restrict__ sq, int* __restrict__ pq) {
  const int b = blockIdx.x;
  const int t = threadIdx.x;
  __shared__ int cnt[256];
  __shared__ int totalS;
  const unsigned char* mb = mask + b * SS;
  unsigned char m[8];
  int c = 0;
#pragma unroll
  for (int j = 0; j < 8; ++j) { m[j] = mb[t * 8 + j]; c += m[j] ? 1 : 0; }
  cnt[t] = c;
  __syncthreads();
  int base = 0;
  for (int i = 0; i < t; ++i) base += cnt[i];
  if (t == 255) totalS = base + c;
  int pos = base;
  int* vb = vidx + b * SS;
#pragma unroll
  for (int j = 0; j < 8; ++j) {
    const int s = t * 8 + j;
    if (m[j]) { vb[pos] = s; ++pos; }
  }
  __syncthreads();
  const int total = totalS;
  if (t == 0) {
    nv[b] = total;
    const int ntile = (total + 255) >> 8;
    {
      const int n = ntile * 12;
      const int qb = atomicAdd(&qctl[1], n);
      int k = 0;
      for (int tt = 0; tt < ntile; ++tt)
        for (int z = 0; z < 3; ++z)
          for (int bn = 0; bn < 4; ++bn)
            queue[qb + (k++)] = (((b << 3) | tt) << 4) | (z << 2) | bn;
    }
    const int nt = (total + 127) >> 7;
    {
      const int ntri = nt * (nt + 1) / 2;
      const int qb = atomicAdd(&qctl[3], ntri);
      for (int t0 = 0; t0 < ntri; ++t0) sq[qb + t0] = (b << 8) | t0;
    }
    {
      const int n = nt * 8;
      const int qb = atomicAdd(&qctl[5], n);
      int k = 0;
      for (int bm = nt - 1; bm >= 0; --bm)
        for (int bn = 0; bn < 8; ++bn)
          pq[qb + (k++)] = (b << 7) | (bm << 3) | bn;
    }
  }
  for (int idx = total + t; idx < SS; idx += 256) vb[idx] = 0;
}

// ------- compact X: Xc[b][j] = bf16(x[b][vidx[j]]), zero-pad to tile --------
__global__ __launch_bounds__(256) void cvt_xc(
    const float* __restrict__ x, const int* __restrict__ vidx,
    const int* __restrict__ nv, unsigned short* __restrict__ Xc) {
  const int j = blockIdx.x;
  const int b = blockIdx.y;
  const int n = nv[b];
  const int ntile = (n + 255) >> 8;
  if (j >= ntile * 256) return;
  const int t = threadIdx.x;
  unsigned short* dst = Xc + ((long)b * SS + j) * HH + t * 4;
  if (j < n) {
    const float* src = x + ((long)b * SS + vidx[b * SS + j]) * HH + t * 4;
    float4 v = *(const float4*)src;
    ushort4 o;
    o.x = f2bf(v.x); o.y = f2bf(v.y); o.z = f2bf(v.z); o.w = f2bf(v.w);
    *(ushort4*)dst = o;
  } else {
    ushort4 z = {0, 0, 0, 0};
    *(ushort4*)dst = z;
  }
}

__global__ void cvt_w3(const float* __restrict__ Wq, const float* __restrict__ Wk,
                       const float* __restrict__ Wv, unsigned short* __restrict__ out) {
  const int z = blockIdx.y;
  const float* src = (z == 0) ? Wq : (z == 1) ? Wk : Wv;
  unsigned short* dst = out + (long)z * (HH * HH);
  const int n4 = HH * HH / 4;
  int i = blockIdx.x * 256 + threadIdx.x;
  for (; i < n4; i += 256 * 256) {
    float4 v = ((const float4*)src)[i];
    ushort4 o;
    o.x = f2bf(v.x); o.y = f2bf(v.y); o.z = f2bf(v.z); o.w = f2bf(v.w);
    ((ushort4*)dst)[i] = o;
  }
}

// ------- per-batch column sums of x (fp32 input; meanV needs ALL rows) ------
__global__ __launch_bounds__(256) void xsum_cols(
    const float* __restrict__ x, float* __restrict__ xsum) {
  const int b = blockIdx.y;
  const int sc = blockIdx.x;
  const int t = threadIdx.x;
  const float* base = x + ((long)b * SS + sc * 64) * HH + t * 4;
  float s0 = 0.f, s1 = 0.f, s2 = 0.f, s3 = 0.f;
#pragma unroll 4
  for (int i = 0; i < 64; ++i) {
    float4 u = *(const float4*)(base + (long)i * HH);
    s0 += u.x; s1 += u.y; s2 += u.z; s3 += u.w;
  }
  float* xs = xsum + b * HH + t * 4;
  atomicAdd(&xs[0], s0); atomicAdd(&xs[1], s1);
  atomicAdd(&xs[2], s2); atomicAdd(&xs[3], s3);
}

// ------- meanV[b][h] = dot(xsum[b], Wv[h]) + 2048*bv[h] ---------------------
__global__ __launch_bounds__(256) void meanv_dot(
    const float* __restrict__ xsum, const unsigned short* __restrict__ Wvbf,
    const float* __restrict__ bv, float* __restrict__ meanV) {
  const int b = blockIdx.y;
  const int wave = threadIdx.x >> 6, lane = threadIdx.x & 63;
  const int h = blockIdx.x * 4 + wave;
  const unsigned short* wrow = Wvbf + (long)h * HH + lane * 16;
  const float* xs = xsum + b * HH + lane * 16;
  float s = 0.f;
#pragma unroll
  for (int j = 0; j < 4; ++j) {
    ushort4 u = *(const ushort4*)(wrow + j * 4);
    s += bf2f(u.x) * xs[j * 4 + 0] + bf2f(u.y) * xs[j * 4 + 1] +
         bf2f(u.z) * xs[j * 4 + 2] + bf2f(u.w) * xs[j * 4 + 3];
  }
#pragma unroll
  for (int off = 32; off > 0; off >>= 1) s += __shfl_down(s, off, 64);
  if (lane == 0) meanV[(long)b * HH + h] = s + 2048.0f * bv[h];
}

// masked query rows -> uniform mean of V
__global__ __launch_bounds__(256) void fixup_masked(
    float* __restrict__ out, const unsigned char* __restrict__ mask,
    const float* __restrict__ sums) {
  const long row = blockIdx.x;
  if (mask[row]) return;
  const long b = row >> 11;
  const int t = threadIdx.x;
  float4 v = ((const float4*)(sums + b * HH))[t];
  v.x *= (1.f / 2048.f); v.y *= (1.f / 2048.f);
  v.z *= (1.f / 2048.f); v.w *= (1.f / 2048.f);
  ((float4*)(out + row * HH))[t] = v;
}

// ===== 256x256 fused QKV — WORK-QUEUE 8-phase core, LINEAR compact-X ========
// All thirds stage A linearly from pre-compacted Xc (r18: kills the r16
// row-gather's L2-defeating scatter). z==2 writes compact Vtc directly.
__global__ __launch_bounds__(512, 2) void gemm256q(
    const unsigned short* __restrict__ Xc,
    const unsigned short* __restrict__ Bbase, long bStride,
    char* __restrict__ Cq, char* __restrict__ Ck, char* __restrict__ VtcOut,
    const float* __restrict__ biasq, const float* __restrict__ biask,
    const float* __restrict__ biasv,
    const int* __restrict__ queue, int* __restrict__ qctl) {
  extern __shared__ char smem[];
  int* bc = (int*)(smem + 131072);
  const int tid = threadIdx.x;
  const int wave = tid >> 6, lane = tid & 63;
  const int wr = wave >> 2, wc = wave & 3;
  const int l15 = lane & 15, l4 = lane >> 4;

  const int srow = tid >> 3;
  const int gslot = (tid & 7) ^ (srow & 7);
  const int ldsStageW = wave << 10;
  const int sw0 = ((l4 ^ (l15 & 7)) << 4);
  const int sw1 = (((4 + l4) ^ (l15 & 7)) << 4);
  const int aB0 = (wr << 14) + l15 * 128 + sw0;
  const int aB1 = (wr << 14) + l15 * 128 + sw1;
  const int bB0 = 32768 + ((wc >> 1) << 14) + (((wc & 1) << 6) + l15) * 128 + sw0;
  const int bB1 = 32768 + ((wc >> 1) << 14) + (((wc & 1) << 6) + l15) * 128 + sw1;
  const int rl0 = (wr << 7) + (l4 << 2);
  const int cl0 = (wc << 6) + l15;
  const int qcnt = qctl[1];

  for (;;) {
    __syncthreads();
    if (tid == 0) *bc = atomicAdd(&qctl[0], 1);
    __syncthreads();
    const int idx = *bc;
    if (idx >= qcnt) break;
    const int e = queue[idx];
    const int bm = e >> 4;
    const int bz = (e >> 2) & 3;
    const int bn = e & 3;
    const int b = bm >> 3;
    const int rInB = (bm & 7) * 256;

    const char* gA = (const char*)Xc + ((long)b * SS + rInB + srow) * 2048 +
                     gslot * 16;
    const char* gB = (const char*)(Bbase + (long)bz * bStride) +
                     ((long)bn * 256 + srow) * 2048 + gslot * 16;

#define STG(kt_, type_, buf_) do { \
    const char* _g = (((type_) < 2) ? gA : gB) + \
                     (((type_) & 1) ? 262144 : 0) + ((long)(kt_) << 7); \
    char* _l = smem + ((buf_) << 16) + (((type_) >> 1) << 15) + \
               (((type_) & 1) << 14) + ldsStageW; \
    gl_lds16(_g, _l); \
    gl_lds16(_g + 131072, _l + 8192); } while (0)

    f32x4 acc[8][4];
    const f32x4 z4 = {0.f, 0.f, 0.f, 0.f};
#pragma unroll
    for (int m = 0; m < 8; ++m)
#pragma unroll
      for (int n = 0; n < 4; ++n) acc[m][n] = z4;

    STG(0, 0, 0); STG(0, 1, 0); STG(0, 2, 0); STG(0, 3, 0);
    STG(1, 0, 1); STG(1, 1, 1); STG(1, 2, 1); STG(1, 3, 1);
    asm volatile("s_waitcnt vmcnt(8)" ::: "memory");
    __builtin_amdgcn_s_barrier();
    __builtin_amdgcn_sched_barrier(0);

    bf16x8 aC[4][2], bLo[2][2], bHi[2][2];

    for (int it = 0; it < 8; ++it) {
#pragma unroll
      for (int g = 0; g < 8; ++g) {
        const int buf = (g < 4) ? 0 : 65536;
        const int q = g & 3;
        if (q == 0) {
#pragma unroll
          for (int mm = 0; mm < 4; ++mm) {
            aC[mm][0] = *(const bf16x8*)(smem + buf + aB0 + mm * 2048);
            aC[mm][1] = *(const bf16x8*)(smem + buf + aB1 + mm * 2048);
          }
#pragma unroll
          for (int nn = 0; nn < 2; ++nn) {
            bLo[nn][0] = *(const bf16x8*)(smem + buf + bB0 + nn * 2048);
            bLo[nn][1] = *(const bf16x8*)(smem + buf + bB1 + nn * 2048);
          }
        } else if (q == 1) {
#pragma unroll
          for (int nn = 0; nn < 2; ++nn) {
            bHi[nn][0] = *(const bf16x8*)(smem + buf + bB0 + (2 + nn) * 2048);
            bHi[nn][1] = *(const bf16x8*)(smem + buf + bB1 + (2 + nn) * 2048);
          }
        } else if (q == 2) {
#pragma unroll
          for (int mm = 0; mm < 4; ++mm) {
            aC[mm][0] = *(const bf16x8*)(smem + buf + aB0 + (4 + mm) * 2048);
            aC[mm][1] = *(const bf16x8*)(smem + buf + aB1 + (4 + mm) * 2048);
          }
        }
        {
          const int u = it * 8 + g - 2;
          if (u >= 0) {
            const int kt = 2 + (u >> 2);
            if (kt < 16) {
              if (g == 0)      STG(kt, 0, 1);
              else if (g == 1) STG(kt, 1, 1);
              else if (g == 2) STG(kt, 2, 0);
              else if (g == 3) STG(kt, 3, 0);
              else if (g == 4) STG(kt, 0, 0);
              else if (g == 5) STG(kt, 1, 0);
              else if (g == 6) STG(kt, 2, 1);
              else             STG(kt, 3, 1);
            }
          }
        }
        __builtin_amdgcn_s_barrier();
        asm volatile("s_waitcnt lgkmcnt(0)" ::: "memory");
        __builtin_amdgcn_sched_barrier(0);
        __builtin_amdgcn_s_setprio(1);
        if (q == 0) {
#pragma unroll
          for (int mm = 0; mm < 4; ++mm)
#pragma unroll
            for (int nn = 0; nn < 2; ++nn) {
              acc[mm][nn] = __builtin_amdgcn_mfma_f32_16x16x32_bf16(
                  aC[mm][0], bLo[nn][0], acc[mm][nn], 0, 0, 0);
              acc[mm][nn] = __builtin_amdgcn_mfma_f32_16x16x32_bf16(
                  aC[mm][1], bLo[nn][1], acc[mm][nn], 0, 0, 0);
            }
        } else if (q == 1) {
#pragma unroll
          for (int mm = 0; mm < 4; ++mm)
#pragma unroll
            for (int nn = 0; nn < 2; ++nn) {
              acc[mm][2 + nn] = __builtin_amdgcn_mfma_f32_16x16x32_bf16(
                  aC[mm][0], bHi[nn][0], acc[mm][2 + nn], 0, 0, 0);
              acc[mm][2 + nn] = __builtin_amdgcn_mfma_f32_16x16x32_bf16(
                  aC[mm][1], bHi[nn][1], acc[mm][2 + nn], 0, 0, 0);
            }
        } else if (q == 2) {
#pragma unroll
          for (int mm = 0; mm < 4; ++mm)
#pragma unroll
            for (int nn = 0; nn < 2; ++nn) {
              acc[4 + mm][2 + nn] = __builtin_amdgcn_mfma_f32_16x16x32_bf16(
                  aC[mm][0], bHi[nn][0], acc[4 + mm][2 + nn], 0, 0, 0);
              acc[4 + mm][2 + nn] = __builtin_amdgcn_mfma_f32_16x16x32_bf16(
                  aC[mm][1], bHi[nn][1], acc[4 + mm][2 + nn], 0, 0, 0);
            }
        } else {
#pragma unroll
          for (int mm = 0; mm < 4; ++mm)
#pragma unroll
            for (int nn = 0; nn < 2; ++nn) {
              acc[4 + mm][nn] = __builtin_amdgcn_mfma_f32_16x16x32_bf16(
                  aC[mm][0], bLo[nn][0], acc[4 + mm][nn], 0, 0, 0);
              acc[4 + mm][nn] = __builtin_amdgcn_mfma_f32_16x16x32_bf16(
                  aC[mm][1], bLo[nn][1], acc[4 + mm][nn], 0, 0, 0);
            }
        }
        __builtin_amdgcn_s_setprio(0);
        __builtin_amdgcn_sched_barrier(0);
        if (q == 3) {
          if (g == 3 && it == 7)
            asm volatile("s_waitcnt vmcnt(0)" ::: "memory");
          else
            asm volatile("s_waitcnt vmcnt(4)" ::: "memory");
        }
        __builtin_amdgcn_s_barrier();
        asm volatile("" ::: "memory");
      }
    }
#undef STG

    if (bz < 2) {
      const float* bias = (bz == 0) ? biasq : biask;
#pragma unroll
      for (int n = 0; n < 4; ++n) {
        const int cl = cl0 + n * 16;
        const float bv = bias[bn * 256 + cl];
        const int colx = cl ^ (l4 << 4);
#pragma unroll
        for (int m = 0; m < 8; ++m) {
          const int rl = rl0 + m * 16;
#pragma unroll
          for (int r = 0; r < 4; ++r)
            *(unsigned short*)(smem + (rl + r) * 512 + colx * 2) =
                f2bf(acc[m][n][r] + bv);
        }
      }
      __syncthreads();
      unsigned short* C = (unsigned short*)((bz == 0) ? Cq : Ck);
      const long rowg0 = (long)b * SS + rInB;
      const long colb0 = (long)bn * 512;
#pragma unroll
      for (int i = 0; i < 16; ++i) {
        const int s2 = i * 512 + tid;
        const int row = s2 >> 5;
        const int cb = s2 & 31;
        const int lb = (row * 512 + (cb << 4)) ^ (((row >> 2) & 3) << 5);
        *(uint4*)((char*)C + (rowg0 + row) * 2048 + colb0 + (cb << 4)) =
            *(const uint4*)(smem + lb);
      }
    } else {
#pragma unroll
      for (int n = 0; n < 4; ++n) {
        const int h = cl0 + n * 16;
        const float bv = biasv[bn * 256 + h];
        const int xr = (h & 7) << 4;
#pragma unroll
        for (int m = 0; m < 8; ++m) {
          const int s0a = rl0 + m * 16;
          uint2 w;
          w.x = (unsigned)f2bf(acc[m][n][0] + bv) |
                ((unsigned)f2bf(acc[m][n][1] + bv) << 16);
          w.y = (unsigned)f2bf(acc[m][n][2] + bv) |
                ((unsigned)f2bf(acc[m][n][3] + bv) << 16);
          *(uint2*)(smem + h * 512 + ((s0a * 2) ^ xr)) = w;
        }
      }
      __syncthreads();
      char* VtB = VtcOut + (long)b * (SS * HH * 2) + (long)(bm & 7) * 512;
#pragma unroll
      for (int i = 0; i < 16; ++i) {
        const int s2 = i * 512 + tid;
        const int h = s2 >> 5;
        const int cb = s2 & 31;
        const int lb = h * 512 + ((cb << 4) ^ ((h & 7) << 4));
        *(uint4*)(VtB + (long)(bn * 256 + h) * 4096 + cb * 16) =
            *(const uint4*)(smem + lb);
      }
    }
  }
}

// -------- WORK-QUEUE 128x128 core: SCORES (compact, pure triangular) --------
__global__ __launch_bounds__(256, 2) void gemm128s(
    const unsigned short* __restrict__ Qc, const unsigned short* __restrict__ Kc,
    char* __restrict__ scoresBase, const int* __restrict__ sq,
    int* __restrict__ qctl) {
  __shared__ __align__(16) char smem[65536];
  __shared__ int bc;
  const int tid = threadIdx.x;
  const int wave = tid >> 6, lane = tid & 63;
  const int wr = wave >> 1, wc = wave & 1;
  const int l15 = lane & 15, l4 = lane >> 4;

  const int s0 = tid, s1 = tid + 256;
  const int rA0 = ((s0 >> 3) << 1) | (((s0 >> 2) & 1) ^ ((s0 >> 4) & 1));
  const int cA0 = (s0 & 3) ^ (rA0 & 3);
  const int rA1 = ((s1 >> 3) << 1) | (((s1 >> 2) & 1) ^ ((s1 >> 4) & 1));
  const int cA1 = (s1 & 3) ^ (rA1 & 3);
  const int ldsL0 = wave << 10;
  const int ldsL1 = 4096 + (wave << 10);
  const int baseSwz = ((l15 * 64 + (l4 << 4)) ^ ((l15 & 7) << 4));
  const int rdA = (wr << 12) + baseSwz;
  const int rdB = 8192 + (wc << 12) + baseSwz;
  const int rl0 = (wr << 6) + (l4 << 2);
  const int cl0 = (wc << 6) + l15;
  const int qcnt = qctl[3];

  for (;;) {
    __syncthreads();
    if (tid == 0) bc = atomicAdd(&qctl[2], 1);
    __syncthreads();
    const int idx = bc;
    if (idx >= qcnt) break;
    const int e = sq[idx];
    const int bz = e >> 8;
    int t0 = e & 255, bm = 0, a_ = 0;
    while (a_ + bm + 1 <= t0) { ++bm; a_ += bm; }
    const int bn = t0 - a_;

    const unsigned short* A = Qc + (long)bz * SS * HH;
    const unsigned short* B = Kc + (long)bz * SS * HH;
    const char* aG0 = (const char*)A + (long)(bm * 128 + rA0) * 2048 + cA0 * 16;
    const char* aG1 = (const char*)A + (long)(bm * 128 + rA1) * 2048 + cA1 * 16;
    const char* bG0 = (const char*)B + (long)(bn * 128 + rA0) * 2048 + cA0 * 16;
    const char* bG1 = (const char*)B + (long)(bn * 128 + rA1) * 2048 + cA1 * 16;

#define STG(t_) do { \
    char* _p = smem + (((t_) & 3) << 14); \
    const long _ko = (long)(t_) << 6; \
    gl_lds16(aG0 + _ko, _p + ldsL0); \
    gl_lds16(aG1 + _ko, _p + ldsL1); \
    gl_lds16(bG0 + _ko, _p + 8192 + ldsL0); \
    gl_lds16(bG1 + _ko, _p + 8192 + ldsL1); } while (0)

    f32x4 acc[4][4];
    const f32x4 z4 = {0.f, 0.f, 0.f, 0.f};
#pragma unroll
    for (int m = 0; m < 4; ++m)
#pragma unroll
      for (int n = 0; n < 4; ++n) acc[m][n] = z4;

    STG(0); STG(1); STG(2);
    asm volatile("s_waitcnt vmcnt(8)" ::: "memory");
    __builtin_amdgcn_s_barrier();
    __builtin_amdgcn_sched_barrier(0);

    const int kT = 32;
    for (int t = 0; t < kT; ++t) {
      if (t + 3 < kT) STG(t + 3);
      const char* bufp = smem + ((t & 3) << 14);
      bf16x8 af[4], bg[4];
#pragma unroll
      for (int m = 0; m < 4; ++m)
        af[m] = *(const bf16x8*)(bufp + rdA + (m << 10));
#pragma unroll
      for (int n = 0; n < 4; ++n)
        bg[n] = *(const bf16x8*)(bufp + rdB + (n << 10));
      __builtin_amdgcn_s_setprio(1);
#pragma unroll
      for (int m = 0; m < 4; ++m)
#pragma unroll
        for (int n = 0; n < 4; ++n)
          acc[m][n] = __builtin_amdgcn_mfma_f32_16x16x32_bf16(af[m], bg[n],
                                                              acc[m][n], 0, 0, 0);
      __builtin_amdgcn_s_setprio(0);
      __builtin_amdgcn_sched_barrier(0);
      if (t + 3 < kT)       asm volatile("s_waitcnt vmcnt(8)" ::: "memory");
      else if (t + 3 == kT) asm volatile("s_waitcnt vmcnt(4)" ::: "memory");
      else if (t + 2 == kT) asm volatile("s_waitcnt vmcnt(0)" ::: "memory");
      if (t + 1 < kT) {
        __builtin_amdgcn_s_barrier();
        __builtin_amdgcn_sched_barrier(0);
        asm volatile("" ::: "memory");
      }
    }
#undef STG

    char* Ct = scoresBase + (long)bz * BATCH_B + (long)t0 * TILE_B;
    __syncthreads();
#pragma unroll
    for (int m = 0; m < 4; ++m)
#pragma unroll
      for (int r = 0; r < 4; ++r) {
        const int ql = rl0 + m * 16 + r;
        const int qg = bm * 128 + ql;
#pragma unroll
        for (int n = 0; n < 4; ++n) {
          const int kg = bn * 128 + cl0 + n * 16;
          const float v = (kg <= qg) ? acc[m][n][r] * 0.03125f : -1.0e9f;
          const int colx = (cl0 + n * 16) ^ (l4 << 4);
          *(unsigned short*)(smem + ql * 256 + colx * 2) = f2bf(v);
        }
      }
    __syncthreads();
#pragma unroll
    for (int i = 0; i < 8; ++i) {
      const int s2 = i * 256 + tid;
      const int row = s2 >> 4;
      const int cb = s2 & 15;
      const int lb = row * 256 + ((cb << 4) ^ (((row >> 2) & 3) << 5));
      *(uint4*)(Ct + (long)row * 256 + (cb << 4)) = *(const uint4*)(smem + lb);
    }
  }
}

// ------------- softmax over compact causal prefix, bf16 128-tiles -----------
__global__ __launch_bounds__(256) void softmax_tri(char* __restrict__ base,
                                                   const int* __restrict__ nv) {
  const int r = blockIdx.x;
  const int bz = blockIdx.y;
  if (r >= nv[bz]) return;
  const int bm = r >> 7;
  const int w = (bm + 1) << 7;
  char* bb = base + (long)bz * BATCH_B +
             (long)(bm * (bm + 1) / 2) * TILE_B + (long)(r & 127) * 256;
  const int t = threadIdx.x;
  const bool act = (t << 3) < w;
  const int bn = t >> 4;
  const int cl = (t << 3) & 127;
  char* slot = bb + (long)bn * TILE_B + (long)cl * 2;
  float v[8];
  float m = -3.0e38f;
  if (act) {
    ushort4 u0 = ((const ushort4*)slot)[0];
    ushort4 u1 = ((const ushort4*)slot)[1];
    v[0] = bf2f(u0.x); v[1] = bf2f(u0.y); v[2] = bf2f(u0.z); v[3] = bf2f(u0.w);
    v[4] = bf2f(u1.x); v[5] = bf2f(u1.y); v[6] = bf2f(u1.z); v[7] = bf2f(u1.w);
#pragma unroll
    for (int k = 0; k < 8; ++k) m = fmaxf(m, v[k]);
  }
  __shared__ float red[8];
#pragma unroll
  for (int off = 32; off > 0; off >>= 1) m = fmaxf(m, __shfl_down(m, off, 64));
  const int wid = t >> 6, lane = t & 63;
  if (lane == 0) red[wid] = m;
  __syncthreads();
  m = fmaxf(fmaxf(red[0], red[1]), fmaxf(red[2], red[3]));
  float e[8];
  float s = 0.f;
  if (act) {
#pragma unroll
    for (int k = 0; k < 8; ++k) { e[k] = __expf(v[k] - m); s += e[k]; }
  }
#pragma unroll
  for (int off = 32; off > 0; off >>= 1) s += __shfl_down(s, off, 64);
  if (lane == 0) red[4 + wid] = s;
  __syncthreads();
  s = red[4] + red[5] + red[6] + red[7];
  const float inv = 1.0f / s;
  if (act) {
    ushort4 o0, o1;
    o0.x = f2bf(e[0] * inv); o0.y = f2bf(e[1] * inv);
    o0.z = f2bf(e[2] * inv); o0.w = f2bf(e[3] * inv);
    o1.x = f2bf(e[4] * inv); o1.y = f2bf(e[5] * inv);
    o1.z = f2bf(e[6] * inv); o1.w = f2bf(e[7] * inv);
    ((ushort4*)slot)[0] = o0;
    ((ushort4*)slot)[1] = o1;
  }
}

// -------- WORK-QUEUE 128x128 core: PV (compact, scatter output) -------------
__global__ __launch_bounds__(256, 2) void gemm_pv(
    const char* __restrict__ attn, const unsigned short* __restrict__ Vtc,
    float* __restrict__ Out, const int* __restrict__ vidx,
    const int* __restrict__ nv, const int* __restrict__ pq,
    int* __restrict__ qctl) {
  __shared__ __align__(16) char smem[65536];
  __shared__ int bc;
  const int tid = threadIdx.x;
  const int wave = tid >> 6, lane = tid & 63;
  const int wr = wave >> 1, wc = wave & 1;
  const int l15 = lane & 15, l4 = lane >> 4;

  const int s0 = tid, s1 = tid + 256;
  const int rA0 = ((s0 >> 3) << 1) | (((s0 >> 2) & 1) ^ ((s0 >> 4) & 1));
  const int cA0 = (s0 & 3) ^ (rA0 & 3);
  const int rA1 = ((s1 >> 3) << 1) | (((s1 >> 2) & 1) ^ ((s1 >> 4) & 1));
  const int cA1 = (s1 & 3) ^ (rA1 & 3);
  const int ldsL0 = wave << 10;
  const int ldsL1 = 4096 + (wave << 10);
  const int baseSwz = ((l15 * 64 + (l4 << 4)) ^ ((l15 & 7) << 4));
  const int rdA = (wr << 12) + baseSwz;
  const int rdB = 8192 + (wc << 12) + baseSwz;
  const int rl0 = (wr << 6) + (l4 << 2);
  const int cl0 = (wc << 6) + l15;
  const int qcnt = qctl[5];

  for (;;) {
    __syncthreads();
    if (tid == 0) bc = atomicAdd(&qctl[4], 1);
    __syncthreads();
    const int idx = bc;
    if (idx >= qcnt) break;
    const int e = pq[idx];
    const int bz = e >> 7;
    const int bm = (e >> 3) & 15;
    const int bn = e & 7;
    const int nvb = nv[bz];

    const char* Ab = attn + (long)bz * BATCH_B +
                     (long)(bm * (bm + 1) / 2) * TILE_B;
    const unsigned short* B = Vtc + (long)bz * SS * HH;
    const char* aB0 = Ab + (long)rA0 * 256 + cA0 * 16;
    const char* aB1 = Ab + (long)rA1 * 256 + cA1 * 16;
    const char* bG0 = (const char*)(B + (long)(bn * 128 + rA0) * SS) + cA0 * 16;
    const char* bG1 = (const char*)(B + (long)(bn * 128 + rA1) * SS) + cA1 * 16;

#define STGPV(t_) do { \
    char* _p = smem + (((t_) & 3) << 14); \
    const long _aO = (long)((t_) >> 2) * TILE_B + (long)((t_) & 3) * 64; \
    const long _bO = (long)(t_) << 6; \
    gl_lds16(aB0 + _aO, _p + ldsL0); \
    gl_lds16(aB1 + _aO, _p + ldsL1); \
    gl_lds16(bG0 + _bO, _p + 8192 + ldsL0); \
    gl_lds16(bG1 + _bO, _p + 8192 + ldsL1); } while (0)

    f32x4 acc[4][4];
    const f32x4 z4 = {0.f, 0.f, 0.f, 0.f};
#pragma unroll
    for (int m = 0; m < 4; ++m)
#pragma unroll
      for (int n = 0; n < 4; ++n) acc[m][n] = z4;

    STGPV(0); STGPV(1); STGPV(2);
    asm volatile("s_waitcnt vmcnt(8)" ::: "memory");
    __builtin_amdgcn_s_barrier();
    __builtin_amdgcn_sched_barrier(0);

    const int kT = (bm + 1) * 4;
    for (int t = 0; t < kT; ++t) {
      if (t + 3 < kT) STGPV(t + 3);
      const char* bufp = smem + ((t & 3) << 14);
      bf16x8 af[4], bg[4];
#pragma unroll
      for (int m = 0; m < 4; ++m)
        af[m] = *(const bf16x8*)(bufp + rdA + (m << 10));
#pragma unroll
      for (int n = 0; n < 4; ++n)
        bg[n] = *(const bf16x8*)(bufp + rdB + (n << 10));
      __builtin_amdgcn_s_setprio(1);
#pragma unroll
      for (int m = 0; m < 4; ++m)
#pragma unroll
        for (int n = 0; n < 4; ++n)
          acc[m][n] = __builtin_amdgcn_mfma_f32_16x16x32_bf16(af[m], bg[n],
                                                              acc[m][n], 0, 0, 0);
      __builtin_amdgcn_s_setprio(0);
      __builtin_amdgcn_sched_barrier(0);
      if (t + 3 < kT)       asm volatile("s_waitcnt vmcnt(8)" ::: "memory");
      else if (t + 3 == kT) asm volatile("s_waitcnt vmcnt(4)" ::: "memory");
      else if (t + 2 == kT) asm volatile("s_waitcnt vmcnt(0)" ::: "memory");
      if (t + 1 < kT) {
        __builtin_amdgcn_s_barrier();
        __builtin_amdgcn_sched_barrier(0);
        asm volatile("" ::: "memory");
      }
    }
#undef STGPV

    __syncthreads();
#pragma unroll
    for (int m = 0; m < 4; ++m)
#pragma unroll
      for (int r = 0; r < 4; ++r) {
        const int ql = rl0 + m * 16 + r;
#pragma unroll
        for (int n = 0; n < 4; ++n) {
          const int colx = (cl0 + n * 16) ^ (l4 << 4);
          *(float*)(smem + ql * 512 + colx * 4) = acc[m][n][r];
        }
      }
    __syncthreads();
    const int* vb = vidx + (long)bz * SS;
#pragma unroll
    for (int i = 0; i < 16; ++i) {
      const int s2 = i * 256 + tid;
      const int row = s2 >> 5;
      const int cb = s2 & 31;
      const int lb = (row * 512 + (cb << 4)) ^ (((row >> 2) & 3) << 6);
      const int crow = bm * 128 + row;
      if (crow < nvb) {
        const int orig = vb[crow];
        *(uint4*)((char*)Out + (((long)bz * SS + orig) * HH) * 4 +
                  (long)bn * 512 + (cb << 4)) = *(const uint4*)(smem + lb);
      }
    }
  }
}

extern "C" void kernel_launch(void* const* d_in, const int* in_sizes, int n_in,
                              void* d_out, int out_size, void* d_ws, size_t ws_size,
                              hipStream_t stream) {
  (void)in_sizes; (void)n_in; (void)out_size; (void)ws_size;
  const float* x = (const float*)d_in[0];
  const unsigned char* mask_raw = (const unsigned char*)d_in[1];
  const float* Wq = (const float*)d_in[2];
  const float* bq = (const float*)d_in[3];
  const float* Wk = (const float*)d_in[4];
  const float* bk = (const float*)d_in[5];
  const float* Wv = (const float*)d_in[6];
  const float* bv = (const float*)d_in[7];
  char* ws = (char*)d_ws;

  unsigned short* Xc = (unsigned short*)(ws + OFF_XC);
  unsigned short* Wbf = (unsigned short*)(ws + OFF_WBF);
  unsigned short* Qc = (unsigned short*)(ws + OFF_Q);
  unsigned short* Kc = (unsigned short*)(ws + OFF_K);
  unsigned short* Vtc = (unsigned short*)(ws + OFF_VTC);
  unsigned char* mask = (unsigned char*)(ws + OFF_MASK);
  float* meanV = (float*)(ws + OFF_MEANV);
  int* vidx = (int*)(ws + OFF_VIDX);
  int* nv = (int*)(ws + OFF_NV);
  float* xsum = (float*)(ws + OFF_XSUM);
  int* qctl = (int*)(ws + OFF_QCTL);
  int* queue = (int*)(ws + OFF_QUEUE);
  int* sq = (int*)(ws + OFF_SQ);
  int* pq = (int*)(ws + OFF_PQ);

  (void)hipFuncSetAttribute((const void*)gemm256q,
                            hipFuncAttributeMaxDynamicSharedMemorySize, 131088);

  // 0. zero queue ctl + xsum; canonicalize mask; build compaction + queues
  hipMemsetAsync(qctl, 0, 32, stream);
  hipMemsetAsync(xsum, 0, (size_t)BB * HH * 4, stream);
  canon_mask<<<1, 1024, 0, stream>>>(mask_raw, mask);
  build_compact<<<BB, 256, 0, stream>>>(mask, vidx, nv, qctl, queue, sq, pq);

  // 1. compact X (fp32 gather -> bf16, zero-padded); weights -> bf16
  cvt_xc<<<dim3(SS, BB), 256, 0, stream>>>(x, vidx, nv, Xc);
  cvt_w3<<<dim3(256, 3), 256, 0, stream>>>(Wq, Wk, Wv, Wbf);

  // 2. meanV via column sums of full fp32 x
  xsum_cols<<<dim3(32, BB), 256, 0, stream>>>(x, xsum);
  meanv_dot<<<dim3(HH / 4, BB), 256, 0, stream>>>(
      xsum, Wbf + 2 * HH * HH, bv, meanV);

  // 3. fused QKV, work-queue, LINEAR compact-X staging
  gemm256q<<<256, 512, 131088, stream>>>(
      Xc, Wbf, (long)HH * HH,
      (char*)Qc, (char*)Kc, (char*)Vtc, bq, bk, bv, queue, qctl);

  // 4. scores, work-queue
  gemm128s<<<512, 256, 0, stream>>>(Qc, Kc, ws + OFF_SCORES, sq, qctl);

  // 5. softmax over compact causal prefix
  softmax_tri<<<dim3(SS, BB), 256, 0, stream>>>(ws + OFF_SCORES, nv);

  // 6. PV, work-queue (longest-first entries)
  gemm_pv<<<512, 256, 0, stream>>>(
      ws + OFF_SCORES, Vtc, (float*)d_out, vidx, nv, pq, qctl);

  // 7. masked query rows -> uniform mean of V
  fixup_masked<<<BB * SS, 256, 0, stream>>>((float*)d_out, mask, meanV);
}